// Round 1
// baseline (2648.908 us; speedup 1.0000x reference)
//
#include <hip/hip_runtime.h>
#include <math.h>

#define BS_ 8
#define B_  4
#define M_  2048
#define D_  128
#define N_  1024
#define NEG (-1e30f)

__device__ __forceinline__ float softplus_(float x) {
    return (x > 20.0f) ? x : log1pf(expf(x));
}
// single-accumulator, ascending-d FMA order; MUST be identical in R1 and R2
__device__ __forceinline__ float dot4_acc(float4 a, float4 b, float acc) {
    acc = fmaf(a.x, b.x, acc);
    acc = fmaf(a.y, b.y, acc);
    acc = fmaf(a.z, b.z, acc);
    acc = fmaf(a.w, b.w, acc);
    return acc;
}

// ---------------------------------------------------------------------------
// Kernel 1: 2-step attention, flash-style, 32 rows per block.
// grid (32, 8), 256 threads. Writes y_em.
// ---------------------------------------------------------------------------
__global__ __launch_bounds__(256, 2) void attn_k(
    const float* __restrict__ seed, const float* __restrict__ emK,
    const float* __restrict__ emV, const float* __restrict__ emS,
    const float* __restrict__ w1, const float* __restrict__ w2,
    const float* __restrict__ gb, const float* __restrict__ raw_tau,
    const int* __restrict__ bp, float* __restrict__ yem)
{
    __shared__ float yt[32][132];   // y rows (padded: 132%32=4 -> banks spread)
    __shared__ float kt[64][132];   // K tile, reused for V tile
    __shared__ float st[32][68];    // scores -> probabilities
    __shared__ float mrun[32], lsum[32], fct[32];
    __shared__ float sbt[64];

    const int tid  = threadIdx.x;
    const int bs   = blockIdx.y;
    const int row0 = blockIdx.x * 32;
    const int b    = bp[0];
    const float tau  = softplus_(raw_tau[b]) + 0.1f;
    const float rtau = 1.0f / tau;

    const float* Kb    = emK + ((size_t)(bs * B_ + b)) * M_ * D_;
    const float* Vb    = emV + ((size_t)(bs * B_ + b)) * M_ * D_;
    const float* Sb    = emS + ((size_t)(bs * B_ + b)) * M_;
    const float* seedB = seed + (size_t)bs * N_ * D_ + (size_t)row0 * D_;

    // y <- seed rows (coalesced float4)
    for (int i = tid; i < 32 * 32; i += 256) {
        int r = i >> 5, c = (i & 31) << 2;
        *(float4*)&yt[r][c] = *(const float4*)&seedB[r * D_ + c];
    }

    const int rq = tid & 7;    // rows rq*4..+3 (S, PV, epilogue)
    const int mq = tid >> 3;   // S: m pair {2mq, 2mq+1} (0..63)
    const int dq = tid >> 3;   // PV/epilogue: d quad dq*4..+3
    const int sr = tid >> 3;   // softmax: row
    const int sj = tid & 7;    // softmax: 8 lanes per row

    float acc[4][4];

    for (int step = 0; step < 2; ++step) {
        #pragma unroll
        for (int i = 0; i < 4; ++i)
            #pragma unroll
            for (int j = 0; j < 4; ++j) acc[i][j] = 0.0f;
        if (tid < 32) { mrun[tid] = NEG; lsum[tid] = 0.0f; }
        __syncthreads();

        for (int mt = 0; mt < M_ / 64; ++mt) {
            // stage K tile
            const float* Kt = Kb + (size_t)(mt * 64) * D_;
            for (int i = tid; i < 64 * 32; i += 256) {
                int r = i >> 5, c = (i & 31) << 2;
                *(float4*)&kt[r][c] = *(const float4*)&Kt[r * D_ + c];
            }
            if (tid < 64) sbt[tid] = Sb[mt * 64 + tid];
            __syncthreads();

            // scores: 4 rows x 2 m per thread
            float s0[4][2];
            #pragma unroll
            for (int i = 0; i < 4; ++i) { s0[i][0] = 0.0f; s0[i][1] = 0.0f; }
            for (int d = 0; d < D_; d += 4) {
                float4 k0 = *(float4*)&kt[mq * 2 + 0][d];
                float4 k1 = *(float4*)&kt[mq * 2 + 1][d];
                #pragma unroll
                for (int i = 0; i < 4; ++i) {
                    float4 yv = *(float4*)&yt[rq * 4 + i][d];
                    s0[i][0] = dot4_acc(yv, k0, s0[i][0]);
                    s0[i][1] = dot4_acc(yv, k1, s0[i][1]);
                }
            }
            #pragma unroll
            for (int i = 0; i < 4; ++i)
                #pragma unroll
                for (int j = 0; j < 2; ++j) {
                    float sv = s0[i][j] * rtau;
                    if (sbt[mq * 2 + j] <= 0.0f) sv = NEG;
                    st[rq * 4 + i][mq * 2 + j] = sv;
                }
            __syncthreads();

            // online softmax update (8 lanes per row)
            {
                float tmax = NEG;
                #pragma unroll
                for (int k = 0; k < 8; ++k) tmax = fmaxf(tmax, st[sr][sj * 8 + k]);
                #pragma unroll
                for (int o = 1; o < 8; o <<= 1) tmax = fmaxf(tmax, __shfl_xor(tmax, o, 8));
                float mold = mrun[sr];
                float mnew = fmaxf(mold, tmax);
                float f = (mnew <= NEG * 0.5f) ? 1.0f : __expf(mold - mnew);
                float ps = 0.0f;
                #pragma unroll
                for (int k = 0; k < 8; ++k) {
                    float sv = st[sr][sj * 8 + k];
                    float p = (sv <= NEG * 0.5f) ? 0.0f : __expf(sv - mnew);
                    st[sr][sj * 8 + k] = p;
                    ps += p;
                }
                #pragma unroll
                for (int o = 1; o < 8; o <<= 1) ps += __shfl_xor(ps, o, 8);
                if (sj == 0) { mrun[sr] = mnew; lsum[sr] = lsum[sr] * f + ps; fct[sr] = f; }
            }
            __syncthreads();

            // rescale acc by row factors; stage V tile into kt
            {
                float fr[4];
                #pragma unroll
                for (int i = 0; i < 4; ++i) fr[i] = fct[rq * 4 + i];
                #pragma unroll
                for (int i = 0; i < 4; ++i)
                    #pragma unroll
                    for (int j = 0; j < 4; ++j) acc[i][j] *= fr[i];
                const float* Vt = Vb + (size_t)(mt * 64) * D_;
                for (int i = tid; i < 64 * 32; i += 256) {
                    int r = i >> 5, c = (i & 31) << 2;
                    *(float4*)&kt[r][c] = *(const float4*)&Vt[r * D_ + c];
                }
            }
            __syncthreads();

            // PV accumulate: acc[i][j] += sum_m p[row_i][m] * V[m][d_j]
            for (int m4 = 0; m4 < 16; ++m4) {
                float4 pr[4];
                #pragma unroll
                for (int i = 0; i < 4; ++i) pr[i] = *(float4*)&st[rq * 4 + i][m4 * 4];
                #pragma unroll
                for (int k = 0; k < 4; ++k) {
                    float4 v = *(float4*)&kt[m4 * 4 + k][dq * 4];
                    #pragma unroll
                    for (int i = 0; i < 4; ++i) {
                        float pk = ((const float*)&pr[i])[k];
                        acc[i][0] = fmaf(pk, v.x, acc[i][0]);
                        acc[i][1] = fmaf(pk, v.y, acc[i][1]);
                        acc[i][2] = fmaf(pk, v.z, acc[i][2]);
                        acc[i][3] = fmaf(pk, v.w, acc[i][3]);
                    }
                }
            }
            __syncthreads();
        } // mt

        // delta -> gate -> y update
        {
            #pragma unroll
            for (int i = 0; i < 4; ++i) {
                float ls  = lsum[rq * 4 + i];
                float inv = (ls > 0.0f) ? 1.0f / ls : 0.0f;
                #pragma unroll
                for (int j = 0; j < 4; ++j) {
                    int d = dq * 4 + j;
                    float delta = acc[i][j] * inv;
                    float yv = yt[rq * 4 + i][d];
                    float g = w1[b * D_ + d] * yv + w2[b * D_ + d] * delta + gb[b * D_ + d];
                    g = 1.0f / (1.0f + __expf(-g));
                    yt[rq * 4 + i][d] = yv + g * delta;
                }
            }
        }
        __syncthreads();
    } // step

    // y_em = y - seed
    float* out = yem + (size_t)bs * N_ * D_ + (size_t)row0 * D_;
    for (int i = tid; i < 32 * 32; i += 256) {
        int r = i >> 5, c = (i & 31) << 2;
        float4 yv = *(float4*)&yt[r][c];
        float4 sv = *(const float4*)&seedB[r * D_ + c];
        float4 o; o.x = yv.x - sv.x; o.y = yv.y - sv.y; o.z = yv.z - sv.z; o.w = yv.w - sv.w;
        *(float4*)&out[r * D_ + c] = o;
    }
}

// ---------------------------------------------------------------------------
// Kernel R1: routing softmax row stats (max, sumexp) -> ws.
// grid (32, 8), 256 threads, 32 n-rows per block.
// ---------------------------------------------------------------------------
__global__ __launch_bounds__(256, 2) void route_stats_k(
    const float* __restrict__ w_cand, const float* __restrict__ emK,
    const float* __restrict__ emS, const float* __restrict__ raw_tau_w,
    const int* __restrict__ bp, float* __restrict__ rmax, float* __restrict__ rsum)
{
    __shared__ float wt[32][132];
    __shared__ float kt[64][132];
    __shared__ float st[32][68];
    __shared__ float mrun[32], lsum[32];
    __shared__ float sbt[64];
    __shared__ float invn[32];

    const int tid = threadIdx.x;
    const int bs  = blockIdx.y;
    const int n0  = blockIdx.x * 32;
    const int b   = bp[0];
    const float tw  = softplus_(raw_tau_w[b]) + 0.1f;
    const float rtw = 1.0f / tw;

    const float* Kb = emK + ((size_t)(bs * B_ + b)) * M_ * D_;
    const float* Sb = emS + ((size_t)(bs * B_ + b)) * M_;
    const float* Wb = w_cand + (size_t)bs * N_ * D_ + (size_t)n0 * D_;

    for (int i = tid; i < 32 * 32; i += 256) {
        int r = i >> 5, c = (i & 31) << 2;
        *(float4*)&wt[r][c] = *(const float4*)&Wb[r * D_ + c];
    }
    if (tid < 32) { mrun[tid] = NEG; lsum[tid] = 0.0f; }
    __syncthreads();
    {   // row inverse norms (same reduction structure as R2)
        int r = tid >> 3, j = tid & 7;
        float ss = 0.0f;
        #pragma unroll
        for (int q = 0; q < 4; ++q) {
            float4 v = *(float4*)&wt[r][j * 16 + q * 4];
            ss = dot4_acc(v, v, ss);
        }
        #pragma unroll
        for (int o = 1; o < 8; o <<= 1) ss += __shfl_xor(ss, o, 8);
        if (j == 0) invn[r] = 1.0f / fmaxf(sqrtf(ss), 1e-12f);
    }
    __syncthreads();

    const int rq = tid & 7, mq = tid >> 3, sr = tid >> 3, sj = tid & 7;

    for (int mt = 0; mt < M_ / 64; ++mt) {
        const float* Kt = Kb + (size_t)(mt * 64) * D_;
        for (int i = tid; i < 64 * 32; i += 256) {
            int r = i >> 5, c = (i & 31) << 2;
            *(float4*)&kt[r][c] = *(const float4*)&Kt[r * D_ + c];
        }
        if (tid < 64) sbt[tid] = Sb[mt * 64 + tid];
        __syncthreads();

        float s0[4][2];
        #pragma unroll
        for (int i = 0; i < 4; ++i) { s0[i][0] = 0.0f; s0[i][1] = 0.0f; }
        for (int d = 0; d < D_; d += 4) {
            float4 k0 = *(float4*)&kt[mq * 2 + 0][d];
            float4 k1 = *(float4*)&kt[mq * 2 + 1][d];
            #pragma unroll
            for (int i = 0; i < 4; ++i) {
                float4 wv = *(float4*)&wt[rq * 4 + i][d];
                s0[i][0] = dot4_acc(wv, k0, s0[i][0]);
                s0[i][1] = dot4_acc(wv, k1, s0[i][1]);
            }
        }
        #pragma unroll
        for (int i = 0; i < 4; ++i)
            #pragma unroll
            for (int j = 0; j < 2; ++j) {
                float sv = s0[i][j] * invn[rq * 4 + i] * rtw;
                if (sbt[mq * 2 + j] <= 0.0f) sv = NEG;
                st[rq * 4 + i][mq * 2 + j] = sv;
            }
        __syncthreads();

        {
            float tmax = NEG;
            #pragma unroll
            for (int k = 0; k < 8; ++k) tmax = fmaxf(tmax, st[sr][sj * 8 + k]);
            #pragma unroll
            for (int o = 1; o < 8; o <<= 1) tmax = fmaxf(tmax, __shfl_xor(tmax, o, 8));
            float mold = mrun[sr];
            float mnew = fmaxf(mold, tmax);
            float f = (mnew <= NEG * 0.5f) ? 1.0f : __expf(mold - mnew);
            float ps = 0.0f;
            #pragma unroll
            for (int k = 0; k < 8; ++k) {
                float sv = st[sr][sj * 8 + k];
                if (sv > NEG * 0.5f) ps += __expf(sv - mnew);
            }
            #pragma unroll
            for (int o = 1; o < 8; o <<= 1) ps += __shfl_xor(ps, o, 8);
            if (sj == 0) { mrun[sr] = mnew; lsum[sr] = lsum[sr] * f + ps; }
        }
        __syncthreads();
    }

    if (tid < 32) {
        rmax[bs * N_ + n0 + tid] = mrun[tid];
        rsum[bs * N_ + n0 + tid] = lsum[tid];
    }
}

// ---------------------------------------------------------------------------
// Kernel R2: recompute route probs, accumulate update_K/update_V/colsum,
// write new_K / new_V / new_S(pre-scale) / new_age.
// grid (64, 8), 256 threads, 32 m-rows per block.
// ---------------------------------------------------------------------------
__global__ __launch_bounds__(256, 2) void update_k(
    const float* __restrict__ w_cand, const float* __restrict__ novelty,
    const float* __restrict__ g_em, const float* __restrict__ emK,
    const float* __restrict__ emV, const float* __restrict__ emS,
    const float* __restrict__ emAge, const float* __restrict__ raw_tau_w,
    const int* __restrict__ bp, const float* __restrict__ rmax,
    const float* __restrict__ rsum, float* __restrict__ outK,
    float* __restrict__ outV, float* __restrict__ outS, float* __restrict__ outA)
{
    __shared__ float kt2[32][132];  // K m-tile (persistent)
    __shared__ float wt[32][132];   // w_cand n-tile; reused as update staging
    __shared__ float st2[32][36];   // weighted_route tile [n][m]
    __shared__ float invn[32], nov[32], rmx[32], rsm[32];
    __shared__ float cs[32];        // column sums
    __shared__ float sbt2[32], normU[32], alpha_s[32];

    const int tid = threadIdx.x;
    const int bs  = blockIdx.y;
    const int m0  = blockIdx.x * 32;
    const int b   = bp[0];
    const float tw  = softplus_(raw_tau_w[b]) + 0.1f;
    const float rtw = 1.0f / tw;
    const float ge  = g_em[bs];

    const float* Kb   = emK + ((size_t)(bs * B_ + b)) * M_ * D_;
    const float* Vb   = emV + ((size_t)(bs * B_ + b)) * M_ * D_;
    const float* Sb   = emS + ((size_t)(bs * B_ + b)) * M_;
    const float* Ageb = emAge + ((size_t)(bs * B_ + b)) * M_;

    for (int i = tid; i < 32 * 32; i += 256) {
        int r = i >> 5, c = (i & 31) << 2;
        *(float4*)&kt2[r][c] = *(const float4*)&Kb[(size_t)(m0 + r) * D_ + c];
    }
    if (tid < 32) { sbt2[tid] = Sb[m0 + tid]; cs[tid] = 0.0f; }
    __syncthreads();

    float accK[4][4], accV[4][4];
    #pragma unroll
    for (int i = 0; i < 4; ++i)
        #pragma unroll
        for (int j = 0; j < 4; ++j) { accK[i][j] = 0.0f; accV[i][j] = 0.0f; }

    const int mq = tid & 7;    // accumulate: m = mq*4..+3
    const int dq = tid >> 3;   // accumulate: d = dq*4..+3
    const int rr = tid >> 4;   // scores: n in {rr, rr+16}
    const int cc = tid & 15;   // scores: m in {cc, cc+16}

    for (int nt = 0; nt < N_ / 32; ++nt) {
        const float* Wt = w_cand + (size_t)bs * N_ * D_ + (size_t)(nt * 32) * D_;
        for (int i = tid; i < 32 * 32; i += 256) {
            int r = i >> 5, c = (i & 31) << 2;
            *(float4*)&wt[r][c] = *(const float4*)&Wt[r * D_ + c];
        }
        __syncthreads();
        {   // inv norms + per-row stats (identical reduction structure to R1)
            int r = tid >> 3, j = tid & 7;
            float ss = 0.0f;
            #pragma unroll
            for (int q = 0; q < 4; ++q) {
                float4 v = *(float4*)&wt[r][j * 16 + q * 4];
                ss = dot4_acc(v, v, ss);
            }
            #pragma unroll
            for (int o = 1; o < 8; o <<= 1) ss += __shfl_xor(ss, o, 8);
            if (j == 0) {
                invn[r] = 1.0f / fmaxf(sqrtf(ss), 1e-12f);
                nov[r]  = novelty[bs * N_ + nt * 32 + r];
                rmx[r]  = rmax[bs * N_ + nt * 32 + r];
                rsm[r]  = rsum[bs * N_ + nt * 32 + r];
            }
        }
        __syncthreads();

        // scores (same per-pair FMA order as R1 -> identical values)
        float sc[2][2] = {{0.0f, 0.0f}, {0.0f, 0.0f}};
        for (int d = 0; d < D_; d += 4) {
            float4 wa = *(float4*)&wt[rr][d];
            float4 wb = *(float4*)&wt[rr + 16][d];
            float4 ka = *(float4*)&kt2[cc][d];
            float4 kb = *(float4*)&kt2[cc + 16][d];
            sc[0][0] = dot4_acc(wa, ka, sc[0][0]);
            sc[0][1] = dot4_acc(wa, kb, sc[0][1]);
            sc[1][0] = dot4_acc(wb, ka, sc[1][0]);
            sc[1][1] = dot4_acc(wb, kb, sc[1][1]);
        }
        #pragma unroll
        for (int i = 0; i < 2; ++i)
            #pragma unroll
            for (int j = 0; j < 2; ++j) {
                int n = rr + 16 * i, m = cc + 16 * j;
                float sv = sc[i][j] * invn[n] * rtw;
                float p;
                if (rsm[n] == 0.0f) p = 1.0f / (float)M_;           // nan_to_num -> uniform
                else if (sbt2[m] <= 0.0f) p = 0.0f;                 // masked slot
                else p = __expf(sv - rmx[n]) / rsm[n];
                st2[n][m] = nov[n] * p;
            }
        __syncthreads();

        // column sums (thread m owns column m)
        if (tid < 32) {
            float c = 0.0f;
            #pragma unroll 4
            for (int n = 0; n < 32; ++n) c += st2[n][tid];
            cs[tid] += c;
        }
        // accumulate update_K / update_V
        for (int n = 0; n < 32; ++n) {
            float inv = invn[n];
            float4 wr4 = *(float4*)&st2[n][mq * 4];
            float4 wv  = *(float4*)&wt[n][dq * 4];
            float wnx = wv.x * inv, wny = wv.y * inv, wnz = wv.z * inv, wnw = wv.w * inv;
            #pragma unroll
            for (int i = 0; i < 4; ++i) {
                float w = ((const float*)&wr4)[i];
                accV[i][0] = fmaf(w, wv.x, accV[i][0]);
                accV[i][1] = fmaf(w, wv.y, accV[i][1]);
                accV[i][2] = fmaf(w, wv.z, accV[i][2]);
                accV[i][3] = fmaf(w, wv.w, accV[i][3]);
                accK[i][0] = fmaf(w, wnx, accK[i][0]);
                accK[i][1] = fmaf(w, wny, accK[i][1]);
                accK[i][2] = fmaf(w, wnz, accK[i][2]);
                accK[i][3] = fmaf(w, wnw, accK[i][3]);
            }
        }
        __syncthreads();
    } // nt

    // ---- finalize ----
    float rden[4];
    #pragma unroll
    for (int i = 0; i < 4; ++i) rden[i] = 1.0f / fmaxf(cs[mq * 4 + i], 1e-8f);

    // stage update_K/denom into wt
    #pragma unroll
    for (int i = 0; i < 4; ++i) {
        float4 t;
        t.x = accK[i][0] * rden[i]; t.y = accK[i][1] * rden[i];
        t.z = accK[i][2] * rden[i]; t.w = accK[i][3] * rden[i];
        *(float4*)&wt[mq * 4 + i][dq * 4] = t;
    }
    __syncthreads();
    {   // per-m norms of update_K and alpha
        int r = tid >> 3, j = tid & 7;
        float ss = 0.0f;
        #pragma unroll
        for (int q = 0; q < 4; ++q) {
            float4 v = *(float4*)&wt[r][j * 16 + q * 4];
            ss = dot4_acc(v, v, ss);
        }
        #pragma unroll
        for (int o = 1; o < 8; o <<= 1) ss += __shfl_xor(ss, o, 8);
        if (j == 0) {
            normU[r]   = 1.0f / fmaxf(sqrtf(ss), 1e-12f);
            alpha_s[r] = fminf(ge * cs[r] * (1.0f / (float)N_), 1.0f);
        }
    }
    __syncthreads();

    // new_K = (1-a)*K + a*unit(update_K)
    float* oK = outK + (size_t)bs * M_ * D_ + (size_t)m0 * D_;
    for (int i2 = tid; i2 < 32 * 32; i2 += 256) {
        int m = i2 >> 5, c = (i2 & 31) << 2;
        float a = alpha_s[m], nu = normU[m];
        float4 kv = *(float4*)&kt2[m][c];
        float4 uv = *(float4*)&wt[m][c];
        float4 o;
        o.x = (1.0f - a) * kv.x + a * uv.x * nu;
        o.y = (1.0f - a) * kv.y + a * uv.y * nu;
        o.z = (1.0f - a) * kv.z + a * uv.z * nu;
        o.w = (1.0f - a) * kv.w + a * uv.w * nu;
        *(float4*)&oK[m * D_ + c] = o;
    }
    __syncthreads();

    // stage update_V/denom into wt
    #pragma unroll
    for (int i = 0; i < 4; ++i) {
        float4 t;
        t.x = accV[i][0] * rden[i]; t.y = accV[i][1] * rden[i];
        t.z = accV[i][2] * rden[i]; t.w = accV[i][3] * rden[i];
        *(float4*)&wt[mq * 4 + i][dq * 4] = t;
    }
    __syncthreads();

    // new_V = (1-a)*V + a*update_V
    const float* VbT = Vb + (size_t)m0 * D_;
    float* oV = outV + (size_t)bs * M_ * D_ + (size_t)m0 * D_;
    for (int i2 = tid; i2 < 32 * 32; i2 += 256) {
        int m = i2 >> 5, c = (i2 & 31) << 2;
        float a = alpha_s[m];
        float4 vv = *(const float4*)&VbT[m * D_ + c];
        float4 uv = *(float4*)&wt[m][c];
        float4 o;
        o.x = (1.0f - a) * vv.x + a * uv.x;
        o.y = (1.0f - a) * vv.y + a * uv.y;
        o.z = (1.0f - a) * vv.z + a * uv.z;
        o.w = (1.0f - a) * vv.w + a * uv.w;
        *(float4*)&oV[m * D_ + c] = o;
    }

    if (tid < 32) {
        float a = alpha_s[tid];
        float sp = fminf(fmaxf(sbt2[tid] + a, 0.0f), 3.0f);
        outS[(size_t)bs * M_ + m0 + tid] = sp;
        outA[(size_t)bs * M_ + m0 + tid] = Ageb[m0 + tid] * (1.0f - a);
    }
}

// ---------------------------------------------------------------------------
// Kernel R3: per-bs budget rescale of new_S (in place in d_out).
// ---------------------------------------------------------------------------
__global__ __launch_bounds__(256) void scale_s_k(float* __restrict__ outS)
{
    __shared__ float wsum[4];
    const int bs = blockIdx.x, tid = threadIdx.x;
    float* p = outS + (size_t)bs * M_;
    float s = 0.0f;
    for (int i = tid; i < M_; i += 256) s += p[i];
    #pragma unroll
    for (int o = 32; o >= 1; o >>= 1) s += __shfl_xor(s, o, 64);
    if ((tid & 63) == 0) wsum[tid >> 6] = s;
    __syncthreads();
    float tot = wsum[0] + wsum[1] + wsum[2] + wsum[3];
    float scale = fminf(1.0f, 32.0f / fmaxf(tot, 1e-8f));
    for (int i = tid; i < M_; i += 256) p[i] *= scale;
}

// ---------------------------------------------------------------------------
extern "C" void kernel_launch(void* const* d_in, const int* in_sizes, int n_in,
                              void* d_out, int out_size, void* d_ws, size_t ws_size,
                              hipStream_t stream) {
    (void)in_sizes; (void)n_in; (void)out_size; (void)ws_size;
    const float* seed    = (const float*)d_in[0];
    const float* w_cand  = (const float*)d_in[1];
    const float* novelty = (const float*)d_in[2];
    const float* g_em    = (const float*)d_in[3];
    const float* emK     = (const float*)d_in[4];
    const float* emV     = (const float*)d_in[5];
    const float* emS     = (const float*)d_in[6];
    const float* emAge   = (const float*)d_in[7];
    const float* w1      = (const float*)d_in[8];
    const float* w2      = (const float*)d_in[9];
    const float* gb      = (const float*)d_in[10];
    const float* rt      = (const float*)d_in[11];
    const float* rtw     = (const float*)d_in[12];
    const int*   bp      = (const int*)d_in[13];

    float* out  = (float*)d_out;
    float* yem  = out;                                   // 8*1024*128
    float* outK = out + 1048576;                         // 8*2048*128
    float* outV = out + 3145728;                         // 8*2048*128
    float* outS = out + 5242880;                         // 8*2048
    float* outA = out + 5259264;                         // 8*2048

    float* rmax = (float*)d_ws;                          // 8*1024
    float* rsum = rmax + BS_ * N_;                       // 8*1024

    attn_k<<<dim3(32, 8), 256, 0, stream>>>(seed, emK, emV, emS, w1, w2, gb, rt, bp, yem);
    route_stats_k<<<dim3(32, 8), 256, 0, stream>>>(w_cand, emK, emS, rtw, bp, rmax, rsum);
    update_k<<<dim3(64, 8), 256, 0, stream>>>(w_cand, novelty, g_em, emK, emV, emS, emAge,
                                              rtw, bp, rmax, rsum, outK, outV, outS, outA);
    scale_s_k<<<8, 256, 0, stream>>>(outS);
}

// Round 2
// 903.085 us; speedup vs baseline: 2.9332x; 2.9332x over previous
//
#include <hip/hip_runtime.h>
#include <hip/hip_bf16.h>
#include <math.h>

#define BS_ 8
#define B_  4
#define M_  2048
#define D_  128
#define N_  1024
#define NEG (-1e30f)

typedef unsigned short us_t;
typedef __attribute__((ext_vector_type(8))) short bf8v;   // 8 bf16 (A/B frag)
typedef __attribute__((ext_vector_type(4))) float f4v;    // C/D frag

__device__ __forceinline__ float softplus_(float x) {
    return (x > 20.0f) ? x : log1pf(expf(x));
}
__device__ __forceinline__ float dot4_acc(float4 a, float4 b, float acc) {
    acc = fmaf(a.x, b.x, acc);
    acc = fmaf(a.y, b.y, acc);
    acc = fmaf(a.z, b.z, acc);
    acc = fmaf(a.w, b.w, acc);
    return acc;
}
__device__ __forceinline__ us_t f2bf(float x) {
    __hip_bfloat16 h = __float2bfloat16(x);   // RNE
    return __builtin_bit_cast(us_t, h);
}
// LDS swizzle: XOR bits 3-5 of ushort index with row&7 (16B-group spreading)
__device__ __forceinline__ int swz(int us_idx, int row) { return us_idx ^ ((row & 7) << 3); }

// ---------------------------------------------------------------------------
// conv_k: f32 -> bf16 conversions into ws.
//  bx<32 : K rows (64 per block)  -> Kbf[m][d]
//  bx>=32: W n-tile (64 rows)     -> Wn[n][d] (normed), WnT[d][n], WcT[d][n]
// ---------------------------------------------------------------------------
__global__ __launch_bounds__(256, 2) void conv_k(
    const float* __restrict__ w_cand, const float* __restrict__ emK,
    const int* __restrict__ bp,
    us_t* __restrict__ Kbf, us_t* __restrict__ Wng,
    us_t* __restrict__ WnTg, us_t* __restrict__ WcTg)
{
    __shared__ float wt[64][132];
    __shared__ float invn[64];
    const int tid = threadIdx.x;
    const int bs  = blockIdx.y;
    const int bx  = blockIdx.x;
    const int b   = bp[0];

    if (bx < 32) {
        const float* src = emK + ((size_t)(bs * B_ + b)) * M_ * D_ + (size_t)bx * 64 * D_;
        us_t* dst = Kbf + (size_t)bs * M_ * D_ + (size_t)bx * 64 * D_;
        for (int i = tid; i < 64 * 128 / 4; i += 256) {
            float4 v = ((const float4*)src)[i];
            ushort4 o;
            o.x = f2bf(v.x); o.y = f2bf(v.y); o.z = f2bf(v.z); o.w = f2bf(v.w);
            ((ushort4*)dst)[i] = o;
        }
        return;
    }
    const int n0 = (bx - 32) * 64;
    const float* Wb = w_cand + (size_t)bs * N_ * D_ + (size_t)n0 * D_;
    for (int c = tid; c < 64 * 32; c += 256) {
        int row = c >> 5, col = (c & 31) << 2;
        *(float4*)&wt[row][col] = *(const float4*)&Wb[row * D_ + col];
    }
    __syncthreads();
    {
        int r = tid >> 2, j = tid & 3;
        float ss = 0.0f;
        #pragma unroll
        for (int q = 0; q < 8; ++q) {
            float4 v = *(float4*)&wt[r][q * 16 + j * 4];
            ss = dot4_acc(v, v, ss);
        }
        ss += __shfl_xor(ss, 1, 4);
        ss += __shfl_xor(ss, 2, 4);
        if (j == 0) invn[r] = 1.0f / fmaxf(sqrtf(ss), 1e-12f);
    }
    __syncthreads();
    us_t* WnB = Wng + (size_t)bs * N_ * D_ + (size_t)n0 * D_;
    for (int e = tid; e < 8192; e += 256) {
        int row = e >> 7, col = e & 127;
        WnB[row * D_ + col] = f2bf(wt[row][col] * invn[row]);
    }
    us_t* WnTB = WnTg + (size_t)bs * D_ * N_;
    us_t* WcTB = WcTg + (size_t)bs * D_ * N_;
    for (int e = tid; e < 8192; e += 256) {
        int d = e >> 6, n = e & 63;
        float v = wt[n][d];
        WnTB[d * N_ + n0 + n] = f2bf(v * invn[n]);
        WcTB[d * N_ + n0 + n] = f2bf(v);
    }
}

// ---------------------------------------------------------------------------
// stats_k: routing softmax column stats over half of M, via MFMA.
// 256 blocks (XCD-chunked): bs, half, 64-n tile. 4 waves; wave = n-frag.
// ---------------------------------------------------------------------------
__global__ __launch_bounds__(256, 2) void stats_k(
    const us_t* __restrict__ Wng, const us_t* __restrict__ Kbf,
    const float* __restrict__ emS, const float* __restrict__ raw_tau_w,
    const int* __restrict__ bp, float* __restrict__ mxW, float* __restrict__ smW)
{
    __shared__ us_t WnL[64 * 128];
    __shared__ us_t KtL[64 * 128];
    __shared__ float sbt[64];

    const int tid = threadIdx.x;
    const int raw = blockIdx.x;
    const int logical = (raw & 7) * 32 + (raw >> 3);   // XCD-chunked
    const int bs = logical >> 5;
    const int rem = logical & 31;
    const int half = rem >> 4;
    const int n0 = (rem & 15) * 64;
    const int mbase = half * 1024;
    const int b = bp[0];
    const float rtw = 1.0f / (softplus_(raw_tau_w[b]) + 0.1f);

    const us_t* WnB = Wng + (size_t)bs * N_ * D_ + (size_t)n0 * D_;
    const us_t* KbB = Kbf + (size_t)bs * M_ * D_ + (size_t)mbase * D_;
    const float* SbB = emS + ((size_t)(bs * B_ + b)) * M_ + mbase;

    for (int c = tid; c < 64 * 16; c += 256) {
        int row = c >> 4, off = (c & 15) << 3;
        uint4 v = *(const uint4*)&WnB[row * 128 + off];
        *(uint4*)&WnL[swz(row * 128 + off, row)] = v;
    }
    __syncthreads();

    const int wave = tid >> 6, lane = tid & 63;
    const int r = lane & 15, kg = lane >> 4;

    bf8v bfr[4];
    #pragma unroll
    for (int kk = 0; kk < 4; ++kk) {
        int row = wave * 16 + r;
        bfr[kk] = *(bf8v*)&WnL[swz(row * 128 + kk * 32 + kg * 8, row)];
    }

    float mx = NEG, sm = 0.0f;

    for (int mt = 0; mt < 16; ++mt) {
        __syncthreads();
        for (int c = tid; c < 64 * 16; c += 256) {
            int row = c >> 4, off = (c & 15) << 3;
            uint4 v = *(const uint4*)&KbB[(size_t)(mt * 64 + row) * 128 + off];
            *(uint4*)&KtL[swz(row * 128 + off, row)] = v;
        }
        if (tid < 64) sbt[tid] = SbB[mt * 64 + tid];
        __syncthreads();

        #pragma unroll
        for (int mf = 0; mf < 4; ++mf) {
            f4v c = {0.f, 0.f, 0.f, 0.f};
            #pragma unroll
            for (int kk = 0; kk < 4; ++kk) {
                int row = mf * 16 + r;
                bf8v a = *(bf8v*)&KtL[swz(row * 128 + kk * 32 + kg * 8, row)];
                c = __builtin_amdgcn_mfma_f32_16x16x32_bf16(a, bfr[kk], c, 0, 0, 0);
            }
            float v[4]; bool act[4];
            float lm = NEG;
            #pragma unroll
            for (int reg = 0; reg < 4; ++reg) {
                int ml = mf * 16 + kg * 4 + reg;
                v[reg] = c[reg] * rtw;
                act[reg] = (sbt[ml] > 0.0f);
                if (act[reg]) lm = fmaxf(lm, v[reg]);
            }
            float mnew = fmaxf(mx, lm);
            if (mnew > -1e29f) {
                float acc = sm * __expf(mx - mnew);
                #pragma unroll
                for (int reg = 0; reg < 4; ++reg)
                    if (act[reg]) acc += __expf(v[reg] - mnew);
                sm = acc; mx = mnew;
            }
        }
    }
    // merge across kg groups
    #pragma unroll
    for (int off = 16; off <= 32; off <<= 1) {
        float omx = __shfl_xor(mx, off, 64);
        float osm = __shfl_xor(sm, off, 64);
        float nm = fmaxf(mx, omx);
        if (nm > -1e29f) sm = sm * __expf(mx - nm) + osm * __expf(omx - nm);
        else sm = 0.0f;
        mx = nm;
    }
    if (kg == 0) {
        int n = n0 + wave * 16 + r;
        mxW[(size_t)half * 8192 + bs * N_ + n] = mx;
        smW[(size_t)half * 8192 + bs * N_ + n] = sm;
    }
}

// ---------------------------------------------------------------------------
// update2_k: per 64-m block: MFMA scores -> P (bf16, LDS) -> MFMA update
// GEMMs + cs; fused finalize writes outK/outV/outS/outA.
// ---------------------------------------------------------------------------
__global__ __launch_bounds__(256, 2) void update2_k(
    const us_t* __restrict__ Kbf, const us_t* __restrict__ Wng,
    const us_t* __restrict__ WnTg, const us_t* __restrict__ WcTg,
    const float* __restrict__ novelty, const float* __restrict__ g_em,
    const float* __restrict__ emK, const float* __restrict__ emV,
    const float* __restrict__ emS, const float* __restrict__ emAge,
    const float* __restrict__ raw_tau_w, const int* __restrict__ bp,
    const float* __restrict__ mxW, const float* __restrict__ smW,
    float* __restrict__ outK, float* __restrict__ outV,
    float* __restrict__ outS, float* __restrict__ outA)
{
    __shared__ us_t KaL[64 * 128];
    __shared__ us_t WnL[64 * 128];
    __shared__ us_t WtT[128 * 64];
    __shared__ us_t WcTl[128 * 64];
    __shared__ us_t Pl[64 * 64];
    __shared__ float mxA[64], rivA[64], punA[64], sbL[64], csL[64], alphaL[64];

    const int tid = threadIdx.x;
    const int raw = blockIdx.x;
    const int logical = (raw & 7) * 32 + (raw >> 3);   // XCD-chunked: one bs per XCD
    const int bs = logical >> 5;
    const int m0 = (logical & 31) * 64;
    const int b = bp[0];
    const float rtw = 1.0f / (softplus_(raw_tau_w[b]) + 0.1f);
    const float ge = g_em[bs];

    const us_t* KaG  = Kbf + (size_t)bs * M_ * D_ + (size_t)m0 * D_;
    const us_t* WnB  = Wng + (size_t)bs * N_ * D_;
    const us_t* WnTB = WnTg + (size_t)bs * D_ * N_;
    const us_t* WcTB = WcTg + (size_t)bs * D_ * N_;

    for (int c = tid; c < 64 * 16; c += 256) {
        int row = c >> 4, off = (c & 15) << 3;
        uint4 v = *(const uint4*)&KaG[row * 128 + off];
        *(uint4*)&KaL[swz(row * 128 + off, row)] = v;
    }
    if (tid < 64) sbL[tid] = emS[((size_t)(bs * B_ + b)) * M_ + m0 + tid];
    __syncthreads();

    const int wave = tid >> 6, lane = tid & 63;
    const int r = lane & 15, kg = lane >> 4;
    const int mf = wave;

    bf8v a_s[4];
    #pragma unroll
    for (int kk = 0; kk < 4; ++kk) {
        int row = mf * 16 + r;
        a_s[kk] = *(bf8v*)&KaL[swz(row * 128 + kk * 32 + kg * 8, row)];
    }
    float sb4[4]; bool act4[4];
    #pragma unroll
    for (int reg = 0; reg < 4; ++reg) {
        sb4[reg] = sbL[mf * 16 + kg * 4 + reg];
        act4[reg] = (sb4[reg] > 0.0f);
    }

    f4v cK[8], cV[8];
    #pragma unroll
    for (int df = 0; df < 8; ++df) { cK[df] = (f4v){0,0,0,0}; cV[df] = (f4v){0,0,0,0}; }
    float csp[4] = {0.f, 0.f, 0.f, 0.f};

    for (int nt = 0; nt < 16; ++nt) {
        const int n0 = nt * 64;
        __syncthreads();
        // stage Wn [64n][128d]
        for (int c = tid; c < 64 * 16; c += 256) {
            int row = c >> 4, off = (c & 15) << 3;
            uint4 v = *(const uint4*)&WnB[(size_t)(n0 + row) * 128 + off];
            *(uint4*)&WnL[swz(row * 128 + off, row)] = v;
        }
        // stage WnT/WcT [128d][64n]
        for (int c = tid; c < 128 * 8; c += 256) {
            int row = c >> 3, off = (c & 7) << 3;
            uint4 v1 = *(const uint4*)&WnTB[(size_t)row * N_ + n0 + off];
            *(uint4*)&WtT[swz(row * 64 + off, row)] = v1;
            uint4 v2 = *(const uint4*)&WcTB[(size_t)row * N_ + n0 + off];
            *(uint4*)&WcTl[swz(row * 64 + off, row)] = v2;
        }
        // per-n softmax constants (merge the two M-halves)
        if (tid < 64) {
            int n = n0 + tid;
            float m0v = mxW[(size_t)bs * N_ + n];
            float m1v = mxW[8192 + (size_t)bs * N_ + n];
            float s0v = smW[(size_t)bs * N_ + n];
            float s1v = smW[8192 + (size_t)bs * N_ + n];
            float MX = fmaxf(m0v, m1v);
            float SM = 0.0f;
            if (MX > -1e29f)
                SM = s0v * __expf(m0v - MX) + s1v * __expf(m1v - MX);
            float nov = novelty[(size_t)bs * N_ + n];
            if (SM > 0.0f) { mxA[tid] = MX; rivA[tid] = nov / SM; punA[tid] = -1.0f; }
            else           { mxA[tid] = 0.0f; rivA[tid] = 0.0f; punA[tid] = nov * (1.0f / (float)M_); }
        }
        __syncthreads();

        // scores + P tile (wave-private rows of Pl)
        #pragma unroll
        for (int nf = 0; nf < 4; ++nf) {
            f4v c = {0.f, 0.f, 0.f, 0.f};
            #pragma unroll
            for (int kk = 0; kk < 4; ++kk) {
                int row = nf * 16 + r;
                bf8v bb = *(bf8v*)&WnL[swz(row * 128 + kk * 32 + kg * 8, row)];
                c = __builtin_amdgcn_mfma_f32_16x16x32_bf16(a_s[kk], bb, c, 0, 0, 0);
            }
            int nl = nf * 16 + r;
            float MX = mxA[nl], RIV = rivA[nl], PU = punA[nl];
            #pragma unroll
            for (int reg = 0; reg < 4; ++reg) {
                float p;
                if (PU >= 0.0f) p = PU;
                else p = act4[reg] ? RIV * __expf(c[reg] * rtw - MX) : 0.0f;
                csp[reg] += p;
                int mrow = mf * 16 + kg * 4 + reg;
                Pl[swz(mrow * 64 + nl, mrow)] = f2bf(p);
            }
        }
        // update GEMM accumulate (reads only this wave's Pl rows)
        #pragma unroll
        for (int kk2 = 0; kk2 < 2; ++kk2) {
            int prow = mf * 16 + r;
            bf8v pa = *(bf8v*)&Pl[swz(prow * 64 + kk2 * 32 + kg * 8, prow)];
            #pragma unroll
            for (int df = 0; df < 8; ++df) {
                int row = df * 16 + r;
                bf8v bk = *(bf8v*)&WtT[swz(row * 64 + kk2 * 32 + kg * 8, row)];
                cK[df] = __builtin_amdgcn_mfma_f32_16x16x32_bf16(pa, bk, cK[df], 0, 0, 0);
                bf8v bv = *(bf8v*)&WcTl[swz(row * 64 + kk2 * 32 + kg * 8, row)];
                cV[df] = __builtin_amdgcn_mfma_f32_16x16x32_bf16(pa, bv, cV[df], 0, 0, 0);
            }
        }
    }

    // cs: reduce over the 16 column-lanes
    #pragma unroll
    for (int reg = 0; reg < 4; ++reg) {
        float v = csp[reg];
        v += __shfl_xor(v, 1, 16);
        v += __shfl_xor(v, 2, 16);
        v += __shfl_xor(v, 4, 16);
        v += __shfl_xor(v, 8, 16);
        csp[reg] = v;
    }
    if (r == 0) {
        #pragma unroll
        for (int reg = 0; reg < 4; ++reg) csL[mf * 16 + kg * 4 + reg] = csp[reg];
    }
    __syncthreads();
    if (tid < 64) alphaL[tid] = fminf(ge * csL[tid] * (1.0f / (float)N_), 1.0f);
    __syncthreads();

    float rden[4], nrm[4];
    #pragma unroll
    for (int reg = 0; reg < 4; ++reg) {
        int ml = mf * 16 + kg * 4 + reg;
        rden[reg] = 1.0f / fmaxf(csL[ml], 1e-8f);
        float s = 0.0f;
        #pragma unroll
        for (int df = 0; df < 8; ++df) {
            float u = cK[df][reg] * rden[reg];
            s += u * u;
        }
        s += __shfl_xor(s, 1, 16);
        s += __shfl_xor(s, 2, 16);
        s += __shfl_xor(s, 4, 16);
        s += __shfl_xor(s, 8, 16);
        nrm[reg] = 1.0f / fmaxf(sqrtf(s), 1e-12f);
    }

    const float* KbG = emK + ((size_t)(bs * B_ + b)) * M_ * D_ + (size_t)m0 * D_;
    const float* VbG = emV + ((size_t)(bs * B_ + b)) * M_ * D_ + (size_t)m0 * D_;
    float* oK = outK + (size_t)bs * M_ * D_ + (size_t)m0 * D_;
    float* oV = outV + (size_t)bs * M_ * D_ + (size_t)m0 * D_;
    #pragma unroll
    for (int reg = 0; reg < 4; ++reg) {
        int ml = mf * 16 + kg * 4 + reg;
        float a = alphaL[ml];
        #pragma unroll
        for (int df = 0; df < 8; ++df) {
            int d = df * 16 + r;
            float uK = cK[df][reg] * rden[reg] * nrm[reg];
            float uV = cV[df][reg] * rden[reg];
            oK[ml * D_ + d] = (1.0f - a) * KbG[ml * D_ + d] + a * uK;
            oV[ml * D_ + d] = (1.0f - a) * VbG[ml * D_ + d] + a * uV;
        }
    }
    if (tid < 64) {
        float a = alphaL[tid];
        float sp = fminf(fmaxf(sbL[tid] + a, 0.0f), 3.0f);
        outS[(size_t)bs * M_ + m0 + tid] = sp;
        outA[(size_t)bs * M_ + m0 + tid] =
            emAge[((size_t)(bs * B_ + b)) * M_ + m0 + tid] * (1.0f - a);
    }
}

// ---------------------------------------------------------------------------
// attn_k: unchanged known-good f32 flash attention (2 steps).
// ---------------------------------------------------------------------------
__global__ __launch_bounds__(256, 2) void attn_k(
    const float* __restrict__ seed, const float* __restrict__ emK,
    const float* __restrict__ emV, const float* __restrict__ emS,
    const float* __restrict__ w1, const float* __restrict__ w2,
    const float* __restrict__ gb, const float* __restrict__ raw_tau,
    const int* __restrict__ bp, float* __restrict__ yem)
{
    __shared__ float yt[32][132];
    __shared__ float kt[64][132];
    __shared__ float st[32][68];
    __shared__ float mrun[32], lsum[32], fct[32];
    __shared__ float sbt[64];

    const int tid  = threadIdx.x;
    const int bs   = blockIdx.y;
    const int row0 = blockIdx.x * 32;
    const int b    = bp[0];
    const float tau  = softplus_(raw_tau[b]) + 0.1f;
    const float rtau = 1.0f / tau;

    const float* Kb    = emK + ((size_t)(bs * B_ + b)) * M_ * D_;
    const float* Vb    = emV + ((size_t)(bs * B_ + b)) * M_ * D_;
    const float* Sb    = emS + ((size_t)(bs * B_ + b)) * M_;
    const float* seedB = seed + (size_t)bs * N_ * D_ + (size_t)row0 * D_;

    for (int i = tid; i < 32 * 32; i += 256) {
        int r = i >> 5, c = (i & 31) << 2;
        *(float4*)&yt[r][c] = *(const float4*)&seedB[r * D_ + c];
    }

    const int rq = tid & 7;
    const int mq = tid >> 3;
    const int dq = tid >> 3;
    const int sr = tid >> 3;
    const int sj = tid & 7;

    float acc[4][4];

    for (int step = 0; step < 2; ++step) {
        #pragma unroll
        for (int i = 0; i < 4; ++i)
            #pragma unroll
            for (int j = 0; j < 4; ++j) acc[i][j] = 0.0f;
        if (tid < 32) { mrun[tid] = NEG; lsum[tid] = 0.0f; }
        __syncthreads();

        for (int mt = 0; mt < M_ / 64; ++mt) {
            const float* Kt = Kb + (size_t)(mt * 64) * D_;
            for (int i = tid; i < 64 * 32; i += 256) {
                int r = i >> 5, c = (i & 31) << 2;
                *(float4*)&kt[r][c] = *(const float4*)&Kt[r * D_ + c];
            }
            if (tid < 64) sbt[tid] = Sb[mt * 64 + tid];
            __syncthreads();

            float s0[4][2];
            #pragma unroll
            for (int i = 0; i < 4; ++i) { s0[i][0] = 0.0f; s0[i][1] = 0.0f; }
            for (int d = 0; d < D_; d += 4) {
                float4 k0 = *(float4*)&kt[mq * 2 + 0][d];
                float4 k1 = *(float4*)&kt[mq * 2 + 1][d];
                #pragma unroll
                for (int i = 0; i < 4; ++i) {
                    float4 yv = *(float4*)&yt[rq * 4 + i][d];
                    s0[i][0] = dot4_acc(yv, k0, s0[i][0]);
                    s0[i][1] = dot4_acc(yv, k1, s0[i][1]);
                }
            }
            #pragma unroll
            for (int i = 0; i < 4; ++i)
                #pragma unroll
                for (int j = 0; j < 2; ++j) {
                    float sv = s0[i][j] * rtau;
                    if (sbt[mq * 2 + j] <= 0.0f) sv = NEG;
                    st[rq * 4 + i][mq * 2 + j] = sv;
                }
            __syncthreads();

            {
                float tmax = NEG;
                #pragma unroll
                for (int k = 0; k < 8; ++k) tmax = fmaxf(tmax, st[sr][sj * 8 + k]);
                #pragma unroll
                for (int o = 1; o < 8; o <<= 1) tmax = fmaxf(tmax, __shfl_xor(tmax, o, 8));
                float mold = mrun[sr];
                float mnew = fmaxf(mold, tmax);
                float f = (mnew <= NEG * 0.5f) ? 1.0f : __expf(mold - mnew);
                float ps = 0.0f;
                #pragma unroll
                for (int k = 0; k < 8; ++k) {
                    float sv = st[sr][sj * 8 + k];
                    float p = (sv <= NEG * 0.5f) ? 0.0f : __expf(sv - mnew);
                    st[sr][sj * 8 + k] = p;
                    ps += p;
                }
                #pragma unroll
                for (int o = 1; o < 8; o <<= 1) ps += __shfl_xor(ps, o, 8);
                if (sj == 0) { mrun[sr] = mnew; lsum[sr] = lsum[sr] * f + ps; fct[sr] = f; }
            }
            __syncthreads();

            {
                float fr[4];
                #pragma unroll
                for (int i = 0; i < 4; ++i) fr[i] = fct[rq * 4 + i];
                #pragma unroll
                for (int i = 0; i < 4; ++i)
                    #pragma unroll
                    for (int j = 0; j < 4; ++j) acc[i][j] *= fr[i];
                const float* Vt = Vb + (size_t)(mt * 64) * D_;
                for (int i = tid; i < 64 * 32; i += 256) {
                    int r = i >> 5, c = (i & 31) << 2;
                    *(float4*)&kt[r][c] = *(const float4*)&Vt[r * D_ + c];
                }
            }
            __syncthreads();

            for (int m4 = 0; m4 < 16; ++m4) {
                float4 pr[4];
                #pragma unroll
                for (int i = 0; i < 4; ++i) pr[i] = *(float4*)&st[rq * 4 + i][m4 * 4];
                #pragma unroll
                for (int k = 0; k < 4; ++k) {
                    float4 v = *(float4*)&kt[m4 * 4 + k][dq * 4];
                    #pragma unroll
                    for (int i = 0; i < 4; ++i) {
                        float pk = ((const float*)&pr[i])[k];
                        acc[i][0] = fmaf(pk, v.x, acc[i][0]);
                        acc[i][1] = fmaf(pk, v.y, acc[i][1]);
                        acc[i][2] = fmaf(pk, v.z, acc[i][2]);
                        acc[i][3] = fmaf(pk, v.w, acc[i][3]);
                    }
                }
            }
            __syncthreads();
        }

        {
            #pragma unroll
            for (int i = 0; i < 4; ++i) {
                float ls  = lsum[rq * 4 + i];
                float inv = (ls > 0.0f) ? 1.0f / ls : 0.0f;
                #pragma unroll
                for (int j = 0; j < 4; ++j) {
                    int d = dq * 4 + j;
                    float delta = acc[i][j] * inv;
                    float yv = yt[rq * 4 + i][d];
                    float g = w1[b * D_ + d] * yv + w2[b * D_ + d] * delta + gb[b * D_ + d];
                    g = 1.0f / (1.0f + __expf(-g));
                    yt[rq * 4 + i][d] = yv + g * delta;
                }
            }
        }
        __syncthreads();
    }

    float* out = yem + (size_t)bs * N_ * D_ + (size_t)row0 * D_;
    for (int i = tid; i < 32 * 32; i += 256) {
        int r = i >> 5, c = (i & 31) << 2;
        float4 yv = *(float4*)&yt[r][c];
        float4 sv = *(const float4*)&seedB[r * D_ + c];
        float4 o; o.x = yv.x - sv.x; o.y = yv.y - sv.y; o.z = yv.z - sv.z; o.w = yv.w - sv.w;
        *(float4*)&out[r * D_ + c] = o;
    }
}

// ---------------------------------------------------------------------------
__global__ __launch_bounds__(256) void scale_s_k(float* __restrict__ outS)
{
    __shared__ float wsum[4];
    const int bs = blockIdx.x, tid = threadIdx.x;
    float* p = outS + (size_t)bs * M_;
    float s = 0.0f;
    for (int i = tid; i < M_; i += 256) s += p[i];
    #pragma unroll
    for (int o = 32; o >= 1; o >>= 1) s += __shfl_xor(s, o, 64);
    if ((tid & 63) == 0) wsum[tid >> 6] = s;
    __syncthreads();
    float tot = wsum[0] + wsum[1] + wsum[2] + wsum[3];
    float scale = fminf(1.0f, 32.0f / fmaxf(tot, 1e-8f));
    for (int i = tid; i < M_; i += 256) p[i] *= scale;
}

// ---------------------------------------------------------------------------
extern "C" void kernel_launch(void* const* d_in, const int* in_sizes, int n_in,
                              void* d_out, int out_size, void* d_ws, size_t ws_size,
                              hipStream_t stream) {
    (void)in_sizes; (void)n_in; (void)out_size; (void)ws_size;
    const float* seed    = (const float*)d_in[0];
    const float* w_cand  = (const float*)d_in[1];
    const float* novelty = (const float*)d_in[2];
    const float* g_em    = (const float*)d_in[3];
    const float* emK     = (const float*)d_in[4];
    const float* emV     = (const float*)d_in[5];
    const float* emS     = (const float*)d_in[6];
    const float* emAge   = (const float*)d_in[7];
    const float* w1      = (const float*)d_in[8];
    const float* w2      = (const float*)d_in[9];
    const float* gb      = (const float*)d_in[10];
    const float* rt      = (const float*)d_in[11];
    const float* rtw     = (const float*)d_in[12];
    const int*   bp      = (const int*)d_in[13];

    float* out  = (float*)d_out;
    float* yem  = out;
    float* outK = out + 1048576;
    float* outV = out + 3145728;
    float* outS = out + 5242880;
    float* outA = out + 5259264;

    us_t* Kbf = (us_t*)d_ws;                               // [8][2048][128]
    us_t* Wng = Kbf + (size_t)BS_ * M_ * D_;               // [8][1024][128]
    us_t* WnT = Wng + (size_t)BS_ * N_ * D_;               // [8][128][1024]
    us_t* WcT = WnT + (size_t)BS_ * D_ * N_;               // [8][128][1024]
    float* mxW = (float*)(WcT + (size_t)BS_ * D_ * N_);    // [2][8][1024]
    float* smW = mxW + 2 * BS_ * N_;                       // [2][8][1024]

    conv_k<<<dim3(48, 8), 256, 0, stream>>>(w_cand, emK, bp, Kbf, Wng, WnT, WcT);
    stats_k<<<dim3(256), 256, 0, stream>>>(Wng, Kbf, emS, rtw, bp, mxW, smW);
    update2_k<<<dim3(256), 256, 0, stream>>>(Kbf, Wng, WnT, WcT, novelty, g_em,
                                             emK, emV, emS, emAge, rtw, bp, mxW, smW,
                                             outK, outV, outS, outA);
    attn_k<<<dim3(32, 8), 256, 0, stream>>>(seed, emK, emV, emS, w1, w2, gb, rt, bp, yem);
    scale_s_k<<<8, 256, 0, stream>>>(outS);
}

// Round 3
// 419.455 us; speedup vs baseline: 6.3151x; 2.1530x over previous
//
#include <hip/hip_runtime.h>
#include <hip/hip_bf16.h>
#include <math.h>

#define BS_ 8
#define B_  4
#define M_  2048
#define D_  128
#define N_  1024
#define NEG (-1e30f)

typedef unsigned short us_t;
typedef __attribute__((ext_vector_type(8))) short bf8v;   // 8 bf16 (A/B frag)
typedef __attribute__((ext_vector_type(4))) float f4v;    // C/D frag

__device__ __forceinline__ float softplus_(float x) {
    return (x > 20.0f) ? x : log1pf(expf(x));
}
__device__ __forceinline__ float dot4_acc(float4 a, float4 b, float acc) {
    acc = fmaf(a.x, b.x, acc);
    acc = fmaf(a.y, b.y, acc);
    acc = fmaf(a.z, b.z, acc);
    acc = fmaf(a.w, b.w, acc);
    return acc;
}
__device__ __forceinline__ us_t f2bf(float x) {
    __hip_bfloat16 h = __float2bfloat16(x);   // RNE
    return __builtin_bit_cast(us_t, h);
}
// LDS swizzle: XOR bits 3-5 of ushort index with row&7 (16B-group spreading)
__device__ __forceinline__ int swz(int us_idx, int row) { return us_idx ^ ((row & 7) << 3); }

// ---------------------------------------------------------------------------
// conv_k: f32 -> bf16 conversions into ws.
//  bx<32   : K rows (64 per block)  -> Kbf[m][d]
//  32..47  : W n-tile (64 rows)     -> Wn[n][d] (normed), WnT[d][n], WcT[d][n]
//  48..79  : V m-tile (64 rows)     -> Vt[d][m] (transposed bf16)
// ---------------------------------------------------------------------------
__global__ __launch_bounds__(256, 2) void conv_k(
    const float* __restrict__ w_cand, const float* __restrict__ emK,
    const float* __restrict__ emV, const int* __restrict__ bp,
    us_t* __restrict__ Kbf, us_t* __restrict__ Wng,
    us_t* __restrict__ WnTg, us_t* __restrict__ WcTg, us_t* __restrict__ Vtg)
{
    __shared__ float wt[64][132];
    __shared__ float invn[64];
    const int tid = threadIdx.x;
    const int bs  = blockIdx.y;
    const int bx  = blockIdx.x;
    const int b   = bp[0];

    if (bx < 32) {
        const float* src = emK + ((size_t)(bs * B_ + b)) * M_ * D_ + (size_t)bx * 64 * D_;
        us_t* dst = Kbf + (size_t)bs * M_ * D_ + (size_t)bx * 64 * D_;
        for (int i = tid; i < 64 * 128 / 4; i += 256) {
            float4 v = ((const float4*)src)[i];
            ushort4 o;
            o.x = f2bf(v.x); o.y = f2bf(v.y); o.z = f2bf(v.z); o.w = f2bf(v.w);
            ((ushort4*)dst)[i] = o;
        }
        return;
    }
    if (bx >= 48) {
        const int m0 = (bx - 48) * 64;
        const float* Vb = emV + ((size_t)(bs * B_ + b)) * M_ * D_ + (size_t)m0 * D_;
        for (int c = tid; c < 64 * 32; c += 256) {
            int row = c >> 5, col = (c & 31) << 2;
            *(float4*)&wt[row][col] = *(const float4*)&Vb[row * D_ + col];
        }
        __syncthreads();
        us_t* VtB = Vtg + (size_t)bs * D_ * M_;
        for (int c = tid; c < 1024; c += 256) {
            int d = c >> 3, mc = c & 7;
            uint4 o;
            o.x = (unsigned)f2bf(wt[mc * 8 + 0][d]) | ((unsigned)f2bf(wt[mc * 8 + 1][d]) << 16);
            o.y = (unsigned)f2bf(wt[mc * 8 + 2][d]) | ((unsigned)f2bf(wt[mc * 8 + 3][d]) << 16);
            o.z = (unsigned)f2bf(wt[mc * 8 + 4][d]) | ((unsigned)f2bf(wt[mc * 8 + 5][d]) << 16);
            o.w = (unsigned)f2bf(wt[mc * 8 + 6][d]) | ((unsigned)f2bf(wt[mc * 8 + 7][d]) << 16);
            *(uint4*)&VtB[(size_t)d * M_ + m0 + mc * 8] = o;
        }
        return;
    }
    const int n0 = (bx - 32) * 64;
    const float* Wb = w_cand + (size_t)bs * N_ * D_ + (size_t)n0 * D_;
    for (int c = tid; c < 64 * 32; c += 256) {
        int row = c >> 5, col = (c & 31) << 2;
        *(float4*)&wt[row][col] = *(const float4*)&Wb[row * D_ + col];
    }
    __syncthreads();
    {
        int r = tid >> 2, j = tid & 3;
        float ss = 0.0f;
        #pragma unroll
        for (int q = 0; q < 8; ++q) {
            float4 v = *(float4*)&wt[r][q * 16 + j * 4];
            ss = dot4_acc(v, v, ss);
        }
        ss += __shfl_xor(ss, 1, 4);
        ss += __shfl_xor(ss, 2, 4);
        if (j == 0) invn[r] = 1.0f / fmaxf(sqrtf(ss), 1e-12f);
    }
    __syncthreads();
    us_t* WnB = Wng + (size_t)bs * N_ * D_ + (size_t)n0 * D_;
    for (int e = tid; e < 8192; e += 256) {
        int row = e >> 7, col = e & 127;
        WnB[row * D_ + col] = f2bf(wt[row][col] * invn[row]);
    }
    us_t* WnTB = WnTg + (size_t)bs * D_ * N_;
    us_t* WcTB = WcTg + (size_t)bs * D_ * N_;
    for (int e = tid; e < 8192; e += 256) {
        int d = e >> 6, n = e & 63;
        float v = wt[n][d];
        WnTB[d * N_ + n0 + n] = f2bf(v * invn[n]);
        WcTB[d * N_ + n0 + n] = f2bf(v);
    }
}

// ---------------------------------------------------------------------------
// attn2_k: 2-step flash attention via bf16 MFMA. 128 blocks (XCD-chunked),
// 256 threads, 64 y-rows per block, wave owns 16 rows.
// ---------------------------------------------------------------------------
__global__ __launch_bounds__(256, 2) void attn2_k(
    const float* __restrict__ seed, const us_t* __restrict__ Kbf,
    const us_t* __restrict__ Vtg, const float* __restrict__ emS,
    const float* __restrict__ w1, const float* __restrict__ w2,
    const float* __restrict__ gb, const float* __restrict__ raw_tau,
    const int* __restrict__ bp, float* __restrict__ yem)
{
    __shared__ float yt[64][132];        // 33.8 KB (f32 y state)
    __shared__ us_t KtL[64 * 128];       // 16 KB
    __shared__ us_t VtL[128 * 64];       // 16 KB
    __shared__ us_t Pl[4 * 16 * 64];     // 8 KB (wave-private P tiles)
    __shared__ float sbt[64];
    __shared__ float w1L[128], w2L[128], gbL[128];

    const int tid = threadIdx.x;
    const int raw = blockIdx.x;
    const int logical = (raw & 7) * 16 + (raw >> 3);   // XCD-chunked (128 = 8*16)
    const int bs = logical >> 4;
    const int row0 = (logical & 15) * 64;
    const int b = bp[0];
    const float rtau = 1.0f / (softplus_(raw_tau[b]) + 0.1f);

    const us_t* KbB = Kbf + (size_t)bs * M_ * D_;
    const us_t* VtB = Vtg + (size_t)bs * D_ * M_;
    const float* SbB = emS + ((size_t)(bs * B_ + b)) * M_;
    const float* seedB = seed + (size_t)bs * N_ * D_ + (size_t)row0 * D_;

    for (int i = tid; i < 64 * 32; i += 256) {
        int rr = i >> 5, cc = (i & 31) << 2;
        *(float4*)&yt[rr][cc] = *(const float4*)&seedB[rr * D_ + cc];
    }
    if (tid < 128) {
        w1L[tid] = w1[b * D_ + tid];
        w2L[tid] = w2[b * D_ + tid];
        gbL[tid] = gb[b * D_ + tid];
    }
    __syncthreads();

    const int wave = tid >> 6, lane = tid & 63;
    const int r = lane & 15, kg = lane >> 4;
    us_t* Pw = Pl + wave * 1024;

    for (int step = 0; step < 2; ++step) {
        // build this wave's y B-fragments (bf16) from LDS f32
        bf8v yb[4];
        #pragma unroll
        for (int kk = 0; kk < 4; ++kk) {
            const float* yp = &yt[wave * 16 + r][kk * 32 + kg * 8];
            bf8v t;
            #pragma unroll
            for (int e = 0; e < 8; ++e) t[e] = (short)f2bf(yp[e]);
            yb[kk] = t;
        }

        f4v cD[8];
        #pragma unroll
        for (int df = 0; df < 8; ++df) cD[df] = (f4v){0.f, 0.f, 0.f, 0.f};
        float mrun = NEG, lsum = 0.0f;

        for (int mt = 0; mt < 32; ++mt) {
            __syncthreads();
            // stage K tile [64m][128d]
            for (int c = tid; c < 1024; c += 256) {
                int row_ = c >> 4, off = (c & 15) << 3;
                uint4 v = *(const uint4*)&KbB[(size_t)(mt * 64 + row_) * 128 + off];
                *(uint4*)&KtL[swz(row_ * 128 + off, row_)] = v;
            }
            // stage Vt tile [128d][64m]
            for (int c = tid; c < 1024; c += 256) {
                int row_ = c >> 3, off = (c & 7) << 3;
                uint4 v = *(const uint4*)&VtB[(size_t)row_ * M_ + mt * 64 + off];
                *(uint4*)&VtL[swz(row_ * 64 + off, row_)] = v;
            }
            if (tid < 64) sbt[tid] = SbB[mt * 64 + tid];
            __syncthreads();

            // scores S[m][n]: lane n = lane&15, m = mf*16 + kg*4 + reg
            float sv[4][4];
            #pragma unroll
            for (int mf = 0; mf < 4; ++mf) {
                f4v c4 = {0.f, 0.f, 0.f, 0.f};
                #pragma unroll
                for (int kk = 0; kk < 4; ++kk) {
                    int row_ = mf * 16 + r;
                    bf8v a = *(bf8v*)&KtL[swz(row_ * 128 + kk * 32 + kg * 8, row_)];
                    c4 = __builtin_amdgcn_mfma_f32_16x16x32_bf16(a, yb[kk], c4, 0, 0, 0);
                }
                #pragma unroll
                for (int reg = 0; reg < 4; ++reg) {
                    int ml = mf * 16 + kg * 4 + reg;
                    sv[mf][reg] = (sbt[ml] > 0.0f) ? c4[reg] * rtau : NEG;
                }
            }
            // per-n tile max (merge across kg lanes)
            float tmax = NEG;
            #pragma unroll
            for (int mf = 0; mf < 4; ++mf)
                #pragma unroll
                for (int reg = 0; reg < 4; ++reg) tmax = fmaxf(tmax, sv[mf][reg]);
            tmax = fmaxf(tmax, __shfl_xor(tmax, 16, 64));
            tmax = fmaxf(tmax, __shfl_xor(tmax, 32, 64));
            float mnew = fmaxf(mrun, tmax);
            float f = (mnew > -1e29f) ? __expf(mrun - mnew) : 1.0f;
            mrun = mnew;

            // p = exp(s - mnew); write bf16 P tile; per-lane partial sum
            float psum = 0.0f;
            #pragma unroll
            for (int mf = 0; mf < 4; ++mf)
                #pragma unroll
                for (int reg = 0; reg < 4; ++reg) {
                    float p = (sv[mf][reg] > -1e29f) ? __expf(sv[mf][reg] - mnew) : 0.0f;
                    psum += p;
                    int ml = mf * 16 + kg * 4 + reg;
                    Pw[swz(r * 64 + ml, r)] = f2bf(p);
                }
            lsum = lsum * f + psum;

            // rescale accumulator by per-n factor (acc n = kg*4+reg)
            float fr[4];
            #pragma unroll
            for (int reg = 0; reg < 4; ++reg) fr[reg] = __shfl(f, kg * 4 + reg, 64);
            #pragma unroll
            for (int df = 0; df < 8; ++df)
                #pragma unroll
                for (int reg = 0; reg < 4; ++reg) cD[df][reg] *= fr[reg];

            // PV: delta[n][d] += P[n][m] * Vt[d][m]
            #pragma unroll
            for (int kk = 0; kk < 2; ++kk) {
                bf8v pa = *(bf8v*)&Pw[swz(r * 64 + kk * 32 + kg * 8, r)];
                #pragma unroll
                for (int df = 0; df < 8; ++df) {
                    int row_ = df * 16 + r;
                    bf8v bv = *(bf8v*)&VtL[swz(row_ * 64 + kk * 32 + kg * 8, row_)];
                    cD[df] = __builtin_amdgcn_mfma_f32_16x16x32_bf16(pa, bv, cD[df], 0, 0, 0);
                }
            }
        } // mt

        // merge lsum across kg (disjoint m subsets)
        lsum += __shfl_xor(lsum, 16, 64);
        lsum += __shfl_xor(lsum, 32, 64);
        float invl = (lsum > 0.0f) ? 1.0f / lsum : 0.0f;   // for n = lane&15

        // gate + y update (wave-private rows)
        #pragma unroll
        for (int reg = 0; reg < 4; ++reg) {
            float inv_n = __shfl(invl, kg * 4 + reg, 64);
            int row_ = wave * 16 + kg * 4 + reg;
            #pragma unroll
            for (int df = 0; df < 8; ++df) {
                int d = df * 16 + r;
                float delta = cD[df][reg] * inv_n;
                float yv = yt[row_][d];
                float g = 1.0f / (1.0f + __expf(-(w1L[d] * yv + w2L[d] * delta + gbL[d])));
                yt[row_][d] = yv + g * delta;
            }
        }
    } // step

    __syncthreads();   // writeout crosses wave-private rows
    float* outp = yem + (size_t)bs * N_ * D_ + (size_t)row0 * D_;
    for (int i = tid; i < 64 * 32; i += 256) {
        int rr = i >> 5, cc = (i & 31) << 2;
        float4 yv = *(float4*)&yt[rr][cc];
        float4 s4 = *(const float4*)&seedB[rr * D_ + cc];
        float4 o; o.x = yv.x - s4.x; o.y = yv.y - s4.y; o.z = yv.z - s4.z; o.w = yv.w - s4.w;
        *(float4*)&outp[rr * D_ + cc] = o;
    }
}

// ---------------------------------------------------------------------------
// stats_k: routing softmax column stats over half of M, via MFMA.
// ---------------------------------------------------------------------------
__global__ __launch_bounds__(256, 2) void stats_k(
    const us_t* __restrict__ Wng, const us_t* __restrict__ Kbf,
    const float* __restrict__ emS, const float* __restrict__ raw_tau_w,
    const int* __restrict__ bp, float* __restrict__ mxW, float* __restrict__ smW)
{
    __shared__ us_t WnL[64 * 128];
    __shared__ us_t KtL[64 * 128];
    __shared__ float sbt[64];

    const int tid = threadIdx.x;
    const int raw = blockIdx.x;
    const int logical = (raw & 7) * 32 + (raw >> 3);   // XCD-chunked
    const int bs = logical >> 5;
    const int rem = logical & 31;
    const int half = rem >> 4;
    const int n0 = (rem & 15) * 64;
    const int mbase = half * 1024;
    const int b = bp[0];
    const float rtw = 1.0f / (softplus_(raw_tau_w[b]) + 0.1f);

    const us_t* WnB = Wng + (size_t)bs * N_ * D_ + (size_t)n0 * D_;
    const us_t* KbB = Kbf + (size_t)bs * M_ * D_ + (size_t)mbase * D_;
    const float* SbB = emS + ((size_t)(bs * B_ + b)) * M_ + mbase;

    for (int c = tid; c < 64 * 16; c += 256) {
        int row = c >> 4, off = (c & 15) << 3;
        uint4 v = *(const uint4*)&WnB[row * 128 + off];
        *(uint4*)&WnL[swz(row * 128 + off, row)] = v;
    }
    __syncthreads();

    const int wave = tid >> 6, lane = tid & 63;
    const int r = lane & 15, kg = lane >> 4;

    bf8v bfr[4];
    #pragma unroll
    for (int kk = 0; kk < 4; ++kk) {
        int row = wave * 16 + r;
        bfr[kk] = *(bf8v*)&WnL[swz(row * 128 + kk * 32 + kg * 8, row)];
    }

    float mx = NEG, sm = 0.0f;

    for (int mt = 0; mt < 16; ++mt) {
        __syncthreads();
        for (int c = tid; c < 64 * 16; c += 256) {
            int row = c >> 4, off = (c & 15) << 3;
            uint4 v = *(const uint4*)&KbB[(size_t)(mt * 64 + row) * 128 + off];
            *(uint4*)&KtL[swz(row * 128 + off, row)] = v;
        }
        if (tid < 64) sbt[tid] = SbB[mt * 64 + tid];
        __syncthreads();

        #pragma unroll
        for (int mf = 0; mf < 4; ++mf) {
            f4v c = {0.f, 0.f, 0.f, 0.f};
            #pragma unroll
            for (int kk = 0; kk < 4; ++kk) {
                int row = mf * 16 + r;
                bf8v a = *(bf8v*)&KtL[swz(row * 128 + kk * 32 + kg * 8, row)];
                c = __builtin_amdgcn_mfma_f32_16x16x32_bf16(a, bfr[kk], c, 0, 0, 0);
            }
            float v[4]; bool act[4];
            float lm = NEG;
            #pragma unroll
            for (int reg = 0; reg < 4; ++reg) {
                int ml = mf * 16 + kg * 4 + reg;
                v[reg] = c[reg] * rtw;
                act[reg] = (sbt[ml] > 0.0f);
                if (act[reg]) lm = fmaxf(lm, v[reg]);
            }
            float mnew = fmaxf(mx, lm);
            if (mnew > -1e29f) {
                float acc = sm * __expf(mx - mnew);
                #pragma unroll
                for (int reg = 0; reg < 4; ++reg)
                    if (act[reg]) acc += __expf(v[reg] - mnew);
                sm = acc; mx = mnew;
            }
        }
    }
    #pragma unroll
    for (int off = 16; off <= 32; off <<= 1) {
        float omx = __shfl_xor(mx, off, 64);
        float osm = __shfl_xor(sm, off, 64);
        float nm = fmaxf(mx, omx);
        if (nm > -1e29f) sm = sm * __expf(mx - nm) + osm * __expf(omx - nm);
        else sm = 0.0f;
        mx = nm;
    }
    if (kg == 0) {
        int n = n0 + wave * 16 + r;
        mxW[(size_t)half * 8192 + bs * N_ + n] = mx;
        smW[(size_t)half * 8192 + bs * N_ + n] = sm;
    }
}

// ---------------------------------------------------------------------------
// update2_k: per 64-m block: MFMA scores -> P (bf16, LDS) -> MFMA update
// GEMMs + cs; fused finalize writes outK/outV/outS/outA.
// ---------------------------------------------------------------------------
__global__ __launch_bounds__(256, 2) void update2_k(
    const us_t* __restrict__ Kbf, const us_t* __restrict__ Wng,
    const us_t* __restrict__ WnTg, const us_t* __restrict__ WcTg,
    const float* __restrict__ novelty, const float* __restrict__ g_em,
    const float* __restrict__ emK, const float* __restrict__ emV,
    const float* __restrict__ emS, const float* __restrict__ emAge,
    const float* __restrict__ raw_tau_w, const int* __restrict__ bp,
    const float* __restrict__ mxW, const float* __restrict__ smW,
    float* __restrict__ outK, float* __restrict__ outV,
    float* __restrict__ outS, float* __restrict__ outA)
{
    __shared__ us_t KaL[64 * 128];
    __shared__ us_t WnL[64 * 128];
    __shared__ us_t WtT[128 * 64];
    __shared__ us_t WcTl[128 * 64];
    __shared__ us_t Pl[64 * 64];
    __shared__ float mxA[64], rivA[64], punA[64], sbL[64], csL[64], alphaL[64];

    const int tid = threadIdx.x;
    const int raw = blockIdx.x;
    const int logical = (raw & 7) * 32 + (raw >> 3);
    const int bs = logical >> 5;
    const int m0 = (logical & 31) * 64;
    const int b = bp[0];
    const float rtw = 1.0f / (softplus_(raw_tau_w[b]) + 0.1f);
    const float ge = g_em[bs];

    const us_t* KaG  = Kbf + (size_t)bs * M_ * D_ + (size_t)m0 * D_;
    const us_t* WnB  = Wng + (size_t)bs * N_ * D_;
    const us_t* WnTB = WnTg + (size_t)bs * D_ * N_;
    const us_t* WcTB = WcTg + (size_t)bs * D_ * N_;

    for (int c = tid; c < 64 * 16; c += 256) {
        int row = c >> 4, off = (c & 15) << 3;
        uint4 v = *(const uint4*)&KaG[row * 128 + off];
        *(uint4*)&KaL[swz(row * 128 + off, row)] = v;
    }
    if (tid < 64) sbL[tid] = emS[((size_t)(bs * B_ + b)) * M_ + m0 + tid];
    __syncthreads();

    const int wave = tid >> 6, lane = tid & 63;
    const int r = lane & 15, kg = lane >> 4;
    const int mf = wave;

    bf8v a_s[4];
    #pragma unroll
    for (int kk = 0; kk < 4; ++kk) {
        int row = mf * 16 + r;
        a_s[kk] = *(bf8v*)&KaL[swz(row * 128 + kk * 32 + kg * 8, row)];
    }
    bool act4[4];
    #pragma unroll
    for (int reg = 0; reg < 4; ++reg) act4[reg] = (sbL[mf * 16 + kg * 4 + reg] > 0.0f);

    f4v cK[8], cV[8];
    #pragma unroll
    for (int df = 0; df < 8; ++df) { cK[df] = (f4v){0,0,0,0}; cV[df] = (f4v){0,0,0,0}; }
    float csp[4] = {0.f, 0.f, 0.f, 0.f};

    for (int nt = 0; nt < 16; ++nt) {
        const int n0 = nt * 64;
        __syncthreads();
        for (int c = tid; c < 64 * 16; c += 256) {
            int row = c >> 4, off = (c & 15) << 3;
            uint4 v = *(const uint4*)&WnB[(size_t)(n0 + row) * 128 + off];
            *(uint4*)&WnL[swz(row * 128 + off, row)] = v;
        }
        for (int c = tid; c < 128 * 8; c += 256) {
            int row = c >> 3, off = (c & 7) << 3;
            uint4 v1 = *(const uint4*)&WnTB[(size_t)row * N_ + n0 + off];
            *(uint4*)&WtT[swz(row * 64 + off, row)] = v1;
            uint4 v2 = *(const uint4*)&WcTB[(size_t)row * N_ + n0 + off];
            *(uint4*)&WcTl[swz(row * 64 + off, row)] = v2;
        }
        if (tid < 64) {
            int n = n0 + tid;
            float m0v = mxW[(size_t)bs * N_ + n];
            float m1v = mxW[8192 + (size_t)bs * N_ + n];
            float s0v = smW[(size_t)bs * N_ + n];
            float s1v = smW[8192 + (size_t)bs * N_ + n];
            float MX = fmaxf(m0v, m1v);
            float SM = 0.0f;
            if (MX > -1e29f)
                SM = s0v * __expf(m0v - MX) + s1v * __expf(m1v - MX);
            float nov = novelty[(size_t)bs * N_ + n];
            if (SM > 0.0f) { mxA[tid] = MX; rivA[tid] = nov / SM; punA[tid] = -1.0f; }
            else           { mxA[tid] = 0.0f; rivA[tid] = 0.0f; punA[tid] = nov * (1.0f / (float)M_); }
        }
        __syncthreads();

        #pragma unroll
        for (int nf = 0; nf < 4; ++nf) {
            f4v c = {0.f, 0.f, 0.f, 0.f};
            #pragma unroll
            for (int kk = 0; kk < 4; ++kk) {
                int row = nf * 16 + r;
                bf8v bb = *(bf8v*)&WnL[swz(row * 128 + kk * 32 + kg * 8, row)];
                c = __builtin_amdgcn_mfma_f32_16x16x32_bf16(a_s[kk], bb, c, 0, 0, 0);
            }
            int nl = nf * 16 + r;
            float MX = mxA[nl], RIV = rivA[nl], PU = punA[nl];
            #pragma unroll
            for (int reg = 0; reg < 4; ++reg) {
                float p;
                if (PU >= 0.0f) p = PU;
                else p = act4[reg] ? RIV * __expf(c[reg] * rtw - MX) : 0.0f;
                csp[reg] += p;
                int mrow = mf * 16 + kg * 4 + reg;
                Pl[swz(mrow * 64 + nl, mrow)] = f2bf(p);
            }
        }
        #pragma unroll
        for (int kk2 = 0; kk2 < 2; ++kk2) {
            int prow = mf * 16 + r;
            bf8v pa = *(bf8v*)&Pl[swz(prow * 64 + kk2 * 32 + kg * 8, prow)];
            #pragma unroll
            for (int df = 0; df < 8; ++df) {
                int row = df * 16 + r;
                bf8v bk = *(bf8v*)&WtT[swz(row * 64 + kk2 * 32 + kg * 8, row)];
                cK[df] = __builtin_amdgcn_mfma_f32_16x16x32_bf16(pa, bk, cK[df], 0, 0, 0);
                bf8v bv = *(bf8v*)&WcTl[swz(row * 64 + kk2 * 32 + kg * 8, row)];
                cV[df] = __builtin_amdgcn_mfma_f32_16x16x32_bf16(pa, bv, cV[df], 0, 0, 0);
            }
        }
    }

    #pragma unroll
    for (int reg = 0; reg < 4; ++reg) {
        float v = csp[reg];
        v += __shfl_xor(v, 1, 16);
        v += __shfl_xor(v, 2, 16);
        v += __shfl_xor(v, 4, 16);
        v += __shfl_xor(v, 8, 16);
        csp[reg] = v;
    }
    if (r == 0) {
        #pragma unroll
        for (int reg = 0; reg < 4; ++reg) csL[mf * 16 + kg * 4 + reg] = csp[reg];
    }
    __syncthreads();
    if (tid < 64) alphaL[tid] = fminf(ge * csL[tid] * (1.0f / (float)N_), 1.0f);
    __syncthreads();

    float rden[4], nrm[4];
    #pragma unroll
    for (int reg = 0; reg < 4; ++reg) {
        int ml = mf * 16 + kg * 4 + reg;
        rden[reg] = 1.0f / fmaxf(csL[ml], 1e-8f);
        float s = 0.0f;
        #pragma unroll
        for (int df = 0; df < 8; ++df) {
            float u = cK[df][reg] * rden[reg];
            s += u * u;
        }
        s += __shfl_xor(s, 1, 16);
        s += __shfl_xor(s, 2, 16);
        s += __shfl_xor(s, 4, 16);
        s += __shfl_xor(s, 8, 16);
        nrm[reg] = 1.0f / fmaxf(sqrtf(s), 1e-12f);
    }

    const float* KbG = emK + ((size_t)(bs * B_ + b)) * M_ * D_ + (size_t)m0 * D_;
    const float* VbG = emV + ((size_t)(bs * B_ + b)) * M_ * D_ + (size_t)m0 * D_;
    float* oK = outK + (size_t)bs * M_ * D_ + (size_t)m0 * D_;
    float* oV = outV + (size_t)bs * M_ * D_ + (size_t)m0 * D_;
    #pragma unroll
    for (int reg = 0; reg < 4; ++reg) {
        int ml = mf * 16 + kg * 4 + reg;
        float a = alphaL[ml];
        #pragma unroll
        for (int df = 0; df < 8; ++df) {
            int d = df * 16 + r;
            float uK = cK[df][reg] * rden[reg] * nrm[reg];
            float uV = cV[df][reg] * rden[reg];
            oK[ml * D_ + d] = (1.0f - a) * KbG[ml * D_ + d] + a * uK;
            oV[ml * D_ + d] = (1.0f - a) * VbG[ml * D_ + d] + a * uV;
        }
    }
    if (tid < 64) {
        float a = alphaL[tid];
        float sp = fminf(fmaxf(sbL[tid] + a, 0.0f), 3.0f);
        outS[(size_t)bs * M_ + m0 + tid] = sp;
        outA[(size_t)bs * M_ + m0 + tid] =
            emAge[((size_t)(bs * B_ + b)) * M_ + m0 + tid] * (1.0f - a);
    }
}

// ---------------------------------------------------------------------------
__global__ __launch_bounds__(256) void scale_s_k(float* __restrict__ outS)
{
    __shared__ float wsum[4];
    const int bs = blockIdx.x, tid = threadIdx.x;
    float* p = outS + (size_t)bs * M_;
    float s = 0.0f;
    for (int i = tid; i < M_; i += 256) s += p[i];
    #pragma unroll
    for (int o = 32; o >= 1; o >>= 1) s += __shfl_xor(s, o, 64);
    if ((tid & 63) == 0) wsum[tid >> 6] = s;
    __syncthreads();
    float tot = wsum[0] + wsum[1] + wsum[2] + wsum[3];
    float scale = fminf(1.0f, 32.0f / fmaxf(tot, 1e-8f));
    for (int i = tid; i < M_; i += 256) p[i] *= scale;
}

// ---------------------------------------------------------------------------
extern "C" void kernel_launch(void* const* d_in, const int* in_sizes, int n_in,
                              void* d_out, int out_size, void* d_ws, size_t ws_size,
                              hipStream_t stream) {
    (void)in_sizes; (void)n_in; (void)out_size; (void)ws_size;
    const float* seed    = (const float*)d_in[0];
    const float* w_cand  = (const float*)d_in[1];
    const float* novelty = (const float*)d_in[2];
    const float* g_em    = (const float*)d_in[3];
    const float* emK     = (const float*)d_in[4];
    const float* emV     = (const float*)d_in[5];
    const float* emS     = (const float*)d_in[6];
    const float* emAge   = (const float*)d_in[7];
    const float* w1      = (const float*)d_in[8];
    const float* w2      = (const float*)d_in[9];
    const float* gb      = (const float*)d_in[10];
    const float* rt      = (const float*)d_in[11];
    const float* rtw     = (const float*)d_in[12];
    const int*   bp      = (const int*)d_in[13];

    float* out  = (float*)d_out;
    float* yem  = out;
    float* outK = out + 1048576;
    float* outV = out + 3145728;
    float* outS = out + 5242880;
    float* outA = out + 5259264;

    us_t* Kbf = (us_t*)d_ws;                               // [8][2048][128]
    us_t* Wng = Kbf + (size_t)BS_ * M_ * D_;               // [8][1024][128]
    us_t* WnT = Wng + (size_t)BS_ * N_ * D_;               // [8][128][1024]
    us_t* WcT = WnT + (size_t)BS_ * D_ * N_;               // [8][128][1024]
    us_t* Vtg = WcT + (size_t)BS_ * D_ * N_;               // [8][128][2048]
    float* mxW = (float*)(Vtg + (size_t)BS_ * D_ * M_);    // [2][8][1024]
    float* smW = mxW + 2 * BS_ * N_;                       // [2][8][1024]

    conv_k<<<dim3(80, 8), 256, 0, stream>>>(w_cand, emK, emV, bp, Kbf, Wng, WnT, WcT, Vtg);
    attn2_k<<<dim3(128), 256, 0, stream>>>(seed, Kbf, Vtg, emS, w1, w2, gb, rt, bp, yem);
    stats_k<<<dim3(256), 256, 0, stream>>>(Wng, Kbf, emS, rtw, bp, mxW, smW);
    update2_k<<<dim3(256), 256, 0, stream>>>(Kbf, Wng, WnT, WcT, novelty, g_em,
                                             emK, emV, emS, emAge, rtw, bp, mxW, smW,
                                             outK, outV, outS, outA);
    scale_s_k<<<8, 256, 0, stream>>>(outS);
}

// Round 4
// 268.226 us; speedup vs baseline: 9.8757x; 1.5638x over previous
//
#include <hip/hip_runtime.h>
#include <hip/hip_bf16.h>
#include <math.h>

#define BS_ 8
#define B_  4
#define M_  2048
#define D_  128
#define N_  1024
#define NEG (-1e30f)

typedef unsigned short us_t;
typedef __attribute__((ext_vector_type(8))) short bf8v;   // 8 bf16 (A/B frag)
typedef __attribute__((ext_vector_type(4))) float f4v;    // C/D frag

__device__ __forceinline__ float softplus_(float x) {
    return (x > 20.0f) ? x : log1pf(expf(x));
}
__device__ __forceinline__ float dot4_acc(float4 a, float4 b, float acc) {
    acc = fmaf(a.x, b.x, acc);
    acc = fmaf(a.y, b.y, acc);
    acc = fmaf(a.z, b.z, acc);
    acc = fmaf(a.w, b.w, acc);
    return acc;
}
__device__ __forceinline__ us_t f2bf(float x) {
    __hip_bfloat16 h = __float2bfloat16(x);   // RNE
    return __builtin_bit_cast(us_t, h);
}
__device__ __forceinline__ float bf2f(us_t u) {
    unsigned v = ((unsigned)u) << 16;
    return __builtin_bit_cast(float, v);
}
// LDS swizzle: XOR bits 3-5 of ushort index with row&7 (16B-group spreading)
__device__ __forceinline__ int swz(int us_idx, int row) { return us_idx ^ ((row & 7) << 3); }

// ---------------------------------------------------------------------------
// conv_k: f32 -> bf16 conversions into ws.
//  bx<32   : K rows (64/block)  -> Kbf[m][d]
//  32..47  : W n-tile (64 rows) -> Wc[n][d], WcT[d][n], invnW[n]
//  48..79  : V m-tile (64 rows) -> Vt[d][m]
// ---------------------------------------------------------------------------
__global__ __launch_bounds__(256, 2) void conv_k(
    const float* __restrict__ w_cand, const float* __restrict__ emK,
    const float* __restrict__ emV, const int* __restrict__ bp,
    us_t* __restrict__ Kbf, us_t* __restrict__ Wcg,
    us_t* __restrict__ WcTg, us_t* __restrict__ Vtg, float* __restrict__ invnW)
{
    __shared__ float wt[64][132];
    __shared__ float invn[64];
    const int tid = threadIdx.x;
    const int bs  = blockIdx.y;
    const int bx  = blockIdx.x;
    const int b   = bp[0];

    if (bx < 32) {
        const float* src = emK + ((size_t)(bs * B_ + b)) * M_ * D_ + (size_t)bx * 64 * D_;
        us_t* dst = Kbf + (size_t)bs * M_ * D_ + (size_t)bx * 64 * D_;
        for (int i = tid; i < 64 * 128 / 4; i += 256) {
            float4 v = ((const float4*)src)[i];
            ushort4 o;
            o.x = f2bf(v.x); o.y = f2bf(v.y); o.z = f2bf(v.z); o.w = f2bf(v.w);
            ((ushort4*)dst)[i] = o;
        }
        return;
    }
    if (bx >= 48) {
        const int m0 = (bx - 48) * 64;
        const float* Vb = emV + ((size_t)(bs * B_ + b)) * M_ * D_ + (size_t)m0 * D_;
        for (int c = tid; c < 64 * 32; c += 256) {
            int row = c >> 5, col = (c & 31) << 2;
            *(float4*)&wt[row][col] = *(const float4*)&Vb[row * D_ + col];
        }
        __syncthreads();
        us_t* VtB = Vtg + (size_t)bs * D_ * M_;
        for (int c = tid; c < 1024; c += 256) {
            int d = c >> 3, mc = c & 7;
            uint4 o;
            o.x = (unsigned)f2bf(wt[mc * 8 + 0][d]) | ((unsigned)f2bf(wt[mc * 8 + 1][d]) << 16);
            o.y = (unsigned)f2bf(wt[mc * 8 + 2][d]) | ((unsigned)f2bf(wt[mc * 8 + 3][d]) << 16);
            o.z = (unsigned)f2bf(wt[mc * 8 + 4][d]) | ((unsigned)f2bf(wt[mc * 8 + 5][d]) << 16);
            o.w = (unsigned)f2bf(wt[mc * 8 + 6][d]) | ((unsigned)f2bf(wt[mc * 8 + 7][d]) << 16);
            *(uint4*)&VtB[(size_t)d * M_ + m0 + mc * 8] = o;
        }
        return;
    }
    const int n0 = (bx - 32) * 64;
    const float* Wb = w_cand + (size_t)bs * N_ * D_ + (size_t)n0 * D_;
    for (int c = tid; c < 64 * 32; c += 256) {
        int row = c >> 5, col = (c & 31) << 2;
        *(float4*)&wt[row][col] = *(const float4*)&Wb[row * D_ + col];
    }
    __syncthreads();
    {
        int r = tid >> 2, j = tid & 3;
        float ss = 0.0f;
        #pragma unroll
        for (int q = 0; q < 8; ++q) {
            float4 v = *(float4*)&wt[r][q * 16 + j * 4];
            ss = dot4_acc(v, v, ss);
        }
        ss += __shfl_xor(ss, 1, 4);
        ss += __shfl_xor(ss, 2, 4);
        if (j == 0) invn[r] = 1.0f / fmaxf(sqrtf(ss), 1e-12f);
    }
    __syncthreads();
    us_t* WcB = Wcg + (size_t)bs * N_ * D_ + (size_t)n0 * D_;
    for (int e = tid; e < 8192; e += 256) {
        int row = e >> 7, col = e & 127;
        WcB[row * D_ + col] = f2bf(wt[row][col]);
    }
    us_t* WcTB = WcTg + (size_t)bs * D_ * N_;
    for (int e = tid; e < 8192; e += 256) {
        int d = e >> 6, n = e & 63;
        WcTB[d * N_ + n0 + n] = f2bf(wt[n][d]);
    }
    if (tid < 64) invnW[(size_t)bs * N_ + n0 + tid] = invn[tid];
}

// ---------------------------------------------------------------------------
// attn_part_k: flash-attention partial over one M-quarter.
// 512 blocks = (bs, n-tile of 64, quarter), XCD-chunked. 4 waves x 16 n-rows.
// Writes normalized partial delta (bf16) + (m,l) per n-row.
// ---------------------------------------------------------------------------
__global__ __launch_bounds__(256, 2) void attn_part_k(
    const float* __restrict__ ySrc, const us_t* __restrict__ Kbf,
    const us_t* __restrict__ Vtg, const float* __restrict__ emS,
    const float* __restrict__ raw_tau, const int* __restrict__ bp,
    us_t* __restrict__ pDelta, float2* __restrict__ pML)
{
    __shared__ us_t KtL[2][8192];
    __shared__ us_t VtL[2][8192];
    __shared__ us_t Pl[4][1024];
    __shared__ float sbt[2][64];

    const int tid = threadIdx.x;
    const int raw = blockIdx.x;
    const int logical = (raw & 7) * 64 + (raw >> 3);   // 512 = 8 XCD * 64
    const int bs = logical >> 6;
    const int rem = logical & 63;
    const int nt = rem >> 2;
    const int q  = rem & 3;
    const int b = bp[0];
    const float rtau = 1.0f / (softplus_(raw_tau[b]) + 0.1f);

    const us_t* KbB = Kbf + (size_t)bs * M_ * D_ + (size_t)(q * 512) * D_;
    const us_t* VtB = Vtg + (size_t)bs * D_ * M_;
    const float* SbB = emS + ((size_t)(bs * B_ + b)) * M_ + q * 512;

    const int wave = tid >> 6, lane = tid & 63;
    const int r = lane & 15, kg = lane >> 4;

    // y fragments (bf16) straight from global f32
    bf8v yb[4];
    {
        const float* yrow = ySrc + ((size_t)bs * N_ + nt * 64 + wave * 16 + r) * D_;
        #pragma unroll
        for (int kk = 0; kk < 4; ++kk) {
            float4 a = *(const float4*)&yrow[kk * 32 + kg * 8];
            float4 c = *(const float4*)&yrow[kk * 32 + kg * 8 + 4];
            bf8v t;
            t[0] = (short)f2bf(a.x); t[1] = (short)f2bf(a.y);
            t[2] = (short)f2bf(a.z); t[3] = (short)f2bf(a.w);
            t[4] = (short)f2bf(c.x); t[5] = (short)f2bf(c.y);
            t[6] = (short)f2bf(c.z); t[7] = (short)f2bf(c.w);
            yb[kk] = t;
        }
    }

    uint4 kr[4], vr[4];
    float sreg = 0.0f;

#define AP_LOAD(t) do {                                                           \
        for (int i = 0; i < 4; ++i) {                                             \
            int c = tid + i * 256;                                                \
            kr[i] = *(const uint4*)&KbB[(size_t)((t) * 64 + (c >> 4)) * D_ + ((c & 15) << 3)]; \
            vr[i] = *(const uint4*)&VtB[(size_t)(c >> 3) * M_ + q * 512 + (t) * 64 + ((c & 7) << 3)]; \
        }                                                                         \
        if (tid < 64) sreg = SbB[(t) * 64 + tid];                                 \
    } while (0)

#define AP_WRITE(bf) do {                                                         \
        for (int i = 0; i < 4; ++i) {                                             \
            int c = tid + i * 256;                                                \
            int ki = (c >> 4) * 128 + ((c & 15) << 3);                            \
            *(uint4*)&KtL[bf][swz(ki, c >> 4)] = kr[i];                           \
            int vi = (c >> 3) * 64 + ((c & 7) << 3);                              \
            *(uint4*)&VtL[bf][swz(vi, c >> 3)] = vr[i];                           \
        }                                                                         \
        if (tid < 64) sbt[bf][tid] = sreg;                                        \
    } while (0)

    f4v cD[8];
    #pragma unroll
    for (int df = 0; df < 8; ++df) cD[df] = (f4v){0.f, 0.f, 0.f, 0.f};
    float mrun = NEG, lsum = 0.0f;

    AP_LOAD(0);
    AP_WRITE(0);
    __syncthreads();

    for (int t = 0; t < 8; ++t) {
        const int cur = t & 1;
        if (t < 7) AP_LOAD(t + 1);

        // scores
        float sv[4][4];
        #pragma unroll
        for (int mf = 0; mf < 4; ++mf) {
            f4v c4 = {0.f, 0.f, 0.f, 0.f};
            #pragma unroll
            for (int kk = 0; kk < 4; ++kk) {
                int row_ = mf * 16 + r;
                bf8v a = *(bf8v*)&KtL[cur][swz(row_ * 128 + kk * 32 + kg * 8, row_)];
                c4 = __builtin_amdgcn_mfma_f32_16x16x32_bf16(a, yb[kk], c4, 0, 0, 0);
            }
            #pragma unroll
            for (int reg = 0; reg < 4; ++reg) {
                int ml = mf * 16 + kg * 4 + reg;
                sv[mf][reg] = (sbt[cur][ml] > 0.0f) ? c4[reg] * rtau : NEG;
            }
        }
        float tmax = NEG;
        #pragma unroll
        for (int mf = 0; mf < 4; ++mf)
            #pragma unroll
            for (int reg = 0; reg < 4; ++reg) tmax = fmaxf(tmax, sv[mf][reg]);
        tmax = fmaxf(tmax, __shfl_xor(tmax, 16, 64));
        tmax = fmaxf(tmax, __shfl_xor(tmax, 32, 64));
        float mnew = fmaxf(mrun, tmax);
        float f = (mnew > -1e29f) ? __expf(mrun - mnew) : 1.0f;
        mrun = mnew;

        float psum = 0.0f;
        #pragma unroll
        for (int mf = 0; mf < 4; ++mf)
            #pragma unroll
            for (int reg = 0; reg < 4; ++reg) {
                float p = (sv[mf][reg] > -1e29f) ? __expf(sv[mf][reg] - mnew) : 0.0f;
                psum += p;
                int ml = mf * 16 + kg * 4 + reg;
                Pl[wave][swz(r * 64 + ml, r)] = f2bf(p);
            }
        lsum = lsum * f + psum;

        float fr[4];
        #pragma unroll
        for (int reg = 0; reg < 4; ++reg) fr[reg] = __shfl(f, kg * 4 + reg, 64);
        #pragma unroll
        for (int df = 0; df < 8; ++df)
            #pragma unroll
            for (int reg = 0; reg < 4; ++reg) cD[df][reg] *= fr[reg];

        #pragma unroll
        for (int kk = 0; kk < 2; ++kk) {
            bf8v pa = *(bf8v*)&Pl[wave][swz(r * 64 + kk * 32 + kg * 8, r)];
            #pragma unroll
            for (int df = 0; df < 8; ++df) {
                int row_ = df * 16 + r;
                bf8v bv = *(bf8v*)&VtL[cur][swz(row_ * 64 + kk * 32 + kg * 8, row_)];
                cD[df] = __builtin_amdgcn_mfma_f32_16x16x32_bf16(pa, bv, cD[df], 0, 0, 0);
            }
        }

        if (t < 7) AP_WRITE(cur ^ 1);
        __syncthreads();
    }
#undef AP_LOAD
#undef AP_WRITE

    lsum += __shfl_xor(lsum, 16, 64);
    lsum += __shfl_xor(lsum, 32, 64);
    float invl = (lsum > 0.0f) ? 1.0f / lsum : 0.0f;

    us_t* pd = pDelta + ((size_t)((bs * 16 + nt) * 4 + q)) * (64 * 128);
    #pragma unroll
    for (int reg = 0; reg < 4; ++reg) {
        float il = __shfl(invl, kg * 4 + reg, 64);
        int nrow = wave * 16 + kg * 4 + reg;
        #pragma unroll
        for (int df = 0; df < 8; ++df)
            pd[nrow * 128 + df * 16 + r] = f2bf(cD[df][reg] * il);
    }
    if (kg == 0) {
        int nrow = wave * 16 + r;
        pML[((size_t)((bs * 16 + nt) * 4 + q)) * 64 + nrow] = make_float2(mrun, lsum);
    }
}

// ---------------------------------------------------------------------------
// attn_merge_k: merge 4 quarters, gate, update y.
// mode 0: write y' (f32). mode 1: write y' - seed (yem).
// ---------------------------------------------------------------------------
__global__ __launch_bounds__(256, 2) void attn_merge_k(
    const float* __restrict__ ySrc, const float* __restrict__ seed,
    const us_t* __restrict__ pDelta, const float2* __restrict__ pML,
    const float* __restrict__ w1, const float* __restrict__ w2,
    const float* __restrict__ gb, const int* __restrict__ bp,
    float* __restrict__ yOut, int mode)
{
    __shared__ float w1L[128], w2L[128], gbL[128];
    const int tid = threadIdx.x, raw = blockIdx.x;
    const int logical = (raw & 7) * 16 + (raw >> 3);
    const int bs = logical >> 4, nt = logical & 15;
    const int b = bp[0];
    if (tid < 128) {
        w1L[tid] = w1[b * D_ + tid];
        w2L[tid] = w2[b * D_ + tid];
        gbL[tid] = gb[b * D_ + tid];
    }
    __syncthreads();
    const int rw = tid >> 2, dj = tid & 3;
    const size_t base = ((size_t)(bs * 16 + nt)) * 4;
    float2 ml0 = pML[(base + 0) * 64 + rw];
    float2 ml1 = pML[(base + 1) * 64 + rw];
    float2 ml2 = pML[(base + 2) * 64 + rw];
    float2 ml3 = pML[(base + 3) * 64 + rw];
    float M = fmaxf(fmaxf(ml0.x, ml1.x), fmaxf(ml2.x, ml3.x));
    float w0 = 0.f, wA = 0.f, wB = 0.f, w3 = 0.f, tot = 0.f;
    if (M > -1e29f) {
        w0 = ml0.y * __expf(ml0.x - M);
        wA = ml1.y * __expf(ml1.x - M);
        wB = ml2.y * __expf(ml2.x - M);
        w3 = ml3.y * __expf(ml3.x - M);
        tot = w0 + wA + wB + w3;
    }
    float inv = (tot > 0.0f) ? 1.0f / tot : 0.0f;
    w0 *= inv; wA *= inv; wB *= inv; w3 *= inv;

    const us_t* pd0 = pDelta + (base + 0) * 8192 + rw * 128;
    const us_t* pd1 = pDelta + (base + 1) * 8192 + rw * 128;
    const us_t* pd2 = pDelta + (base + 2) * 8192 + rw * 128;
    const us_t* pd3 = pDelta + (base + 3) * 8192 + rw * 128;
    const float* yrow = ySrc + ((size_t)bs * N_ + nt * 64 + rw) * D_;
    const float* srow = seed + ((size_t)bs * N_ + nt * 64 + rw) * D_;
    float* orow = yOut + ((size_t)bs * N_ + nt * 64 + rw) * D_;

    #pragma unroll
    for (int e = 0; e < 4; ++e) {
        int d0 = dj * 32 + e * 8;
        uint4 u0 = *(const uint4*)&pd0[d0];
        uint4 u1 = *(const uint4*)&pd1[d0];
        uint4 u2 = *(const uint4*)&pd2[d0];
        uint4 u3 = *(const uint4*)&pd3[d0];
        const us_t* a0 = (const us_t*)&u0;
        const us_t* a1 = (const us_t*)&u1;
        const us_t* a2 = (const us_t*)&u2;
        const us_t* a3 = (const us_t*)&u3;
        float4 ya = *(const float4*)&yrow[d0];
        float4 yc = *(const float4*)&yrow[d0 + 4];
        float yv[8] = {ya.x, ya.y, ya.z, ya.w, yc.x, yc.y, yc.z, yc.w};
        float res[8];
        #pragma unroll
        for (int j = 0; j < 8; ++j) {
            float dl = w0 * bf2f(a0[j]) + wA * bf2f(a1[j]) + wB * bf2f(a2[j]) + w3 * bf2f(a3[j]);
            int d = d0 + j;
            float g = 1.0f / (1.0f + __expf(-(w1L[d] * yv[j] + w2L[d] * dl + gbL[d])));
            res[j] = yv[j] + g * dl;
        }
        if (mode == 1) {
            float4 sa = *(const float4*)&srow[d0];
            float4 sc = *(const float4*)&srow[d0 + 4];
            res[0] -= sa.x; res[1] -= sa.y; res[2] -= sa.z; res[3] -= sa.w;
            res[4] -= sc.x; res[5] -= sc.y; res[6] -= sc.z; res[7] -= sc.w;
        }
        float4 o1; o1.x = res[0]; o1.y = res[1]; o1.z = res[2]; o1.w = res[3];
        float4 o2; o2.x = res[4]; o2.y = res[5]; o2.z = res[6]; o2.w = res[7];
        *(float4*)&orow[d0] = o1;
        *(float4*)&orow[d0 + 4] = o2;
    }
}

// ---------------------------------------------------------------------------
// stats_k: routing score stats over one M-quarter. 512 blocks, dbuf K tiles.
// ---------------------------------------------------------------------------
__global__ __launch_bounds__(256, 2) void stats_k(
    const us_t* __restrict__ Wcg, const us_t* __restrict__ Kbf,
    const float* __restrict__ invnW, const float* __restrict__ emS,
    const float* __restrict__ raw_tau_w, const int* __restrict__ bp,
    float* __restrict__ mxW, float* __restrict__ smW)
{
    __shared__ us_t KtL[2][8192];
    __shared__ float sbt[2][64];

    const int tid = threadIdx.x;
    const int raw = blockIdx.x;
    const int logical = (raw & 7) * 64 + (raw >> 3);
    const int bs = logical >> 6;
    const int rem = logical & 63;
    const int nt = rem >> 2;
    const int q  = rem & 3;
    const int b = bp[0];
    const float rtw = 1.0f / (softplus_(raw_tau_w[b]) + 0.1f);

    const us_t* KbB = Kbf + (size_t)bs * M_ * D_ + (size_t)(q * 512) * D_;
    const float* SbB = emS + ((size_t)(bs * B_ + b)) * M_ + q * 512;

    const int wave = tid >> 6, lane = tid & 63;
    const int r = lane & 15, kg = lane >> 4;
    const int n = nt * 64 + wave * 16 + r;

    bf8v wb[4];
    {
        const us_t* wrow = Wcg + ((size_t)bs * N_ + n) * D_;
        #pragma unroll
        for (int kk = 0; kk < 4; ++kk)
            wb[kk] = *(const bf8v*)&wrow[kk * 32 + kg * 8];
    }
    const float ivn = invnW[(size_t)bs * N_ + n];

    uint4 kr[4];
    float sreg = 0.0f;

#define ST_LOAD(t) do {                                                           \
        for (int i = 0; i < 4; ++i) {                                             \
            int c = tid + i * 256;                                                \
            kr[i] = *(const uint4*)&KbB[(size_t)((t) * 64 + (c >> 4)) * D_ + ((c & 15) << 3)]; \
        }                                                                         \
        if (tid < 64) sreg = SbB[(t) * 64 + tid];                                 \
    } while (0)

#define ST_WRITE(bf) do {                                                         \
        for (int i = 0; i < 4; ++i) {                                             \
            int c = tid + i * 256;                                                \
            int ki = (c >> 4) * 128 + ((c & 15) << 3);                            \
            *(uint4*)&KtL[bf][swz(ki, c >> 4)] = kr[i];                           \
        }                                                                         \
        if (tid < 64) sbt[bf][tid] = sreg;                                        \
    } while (0)

    float mx = NEG, sm = 0.0f;

    ST_LOAD(0);
    ST_WRITE(0);
    __syncthreads();

    for (int t = 0; t < 8; ++t) {
        const int cur = t & 1;
        if (t < 7) ST_LOAD(t + 1);

        #pragma unroll
        for (int mf = 0; mf < 4; ++mf) {
            f4v c4 = {0.f, 0.f, 0.f, 0.f};
            #pragma unroll
            for (int kk = 0; kk < 4; ++kk) {
                int row_ = mf * 16 + r;
                bf8v a = *(bf8v*)&KtL[cur][swz(row_ * 128 + kk * 32 + kg * 8, row_)];
                c4 = __builtin_amdgcn_mfma_f32_16x16x32_bf16(a, wb[kk], c4, 0, 0, 0);
            }
            float v[4]; bool act[4];
            float lm = NEG;
            #pragma unroll
            for (int reg = 0; reg < 4; ++reg) {
                int ml = mf * 16 + kg * 4 + reg;
                v[reg] = c4[reg] * ivn * rtw;
                act[reg] = (sbt[cur][ml] > 0.0f);
                if (act[reg]) lm = fmaxf(lm, v[reg]);
            }
            float mnew = fmaxf(mx, lm);
            if (mnew > -1e29f) {
                float acc = sm * __expf(mx - mnew);
                #pragma unroll
                for (int reg = 0; reg < 4; ++reg)
                    if (act[reg]) acc += __expf(v[reg] - mnew);
                sm = acc; mx = mnew;
            }
        }

        if (t < 7) ST_WRITE(cur ^ 1);
        __syncthreads();
    }
#undef ST_LOAD
#undef ST_WRITE

    #pragma unroll
    for (int off = 16; off <= 32; off <<= 1) {
        float omx = __shfl_xor(mx, off, 64);
        float osm = __shfl_xor(sm, off, 64);
        float nm = fmaxf(mx, omx);
        if (nm > -1e29f) sm = sm * __expf(mx - nm) + osm * __expf(omx - nm);
        else sm = 0.0f;
        mx = nm;
    }
    if (kg == 0) {
        mxW[(size_t)(q * BS_ + bs) * N_ + n] = mx;
        smW[(size_t)(q * BS_ + bs) * N_ + n] = sm;
    }
}

// ---------------------------------------------------------------------------
// stats_fin_k: merge 4 quarters -> per-n softmax constants.
// ---------------------------------------------------------------------------
__global__ __launch_bounds__(256) void stats_fin_k(
    const float* __restrict__ mxW, const float* __restrict__ smW,
    const float* __restrict__ novelty,
    float* __restrict__ mxF, float* __restrict__ rivF, float* __restrict__ punF)
{
    int idx = blockIdx.x * 256 + threadIdx.x;   // 32 blocks * 256 = 8192
    float m[4], s[4];
    #pragma unroll
    for (int q = 0; q < 4; ++q) {
        m[q] = mxW[q * (BS_ * N_) + idx];
        s[q] = smW[q * (BS_ * N_) + idx];
    }
    float MX = fmaxf(fmaxf(m[0], m[1]), fmaxf(m[2], m[3]));
    float SM = 0.0f;
    if (MX > -1e29f) {
        #pragma unroll
        for (int q = 0; q < 4; ++q)
            if (m[q] > -1e29f) SM += s[q] * __expf(m[q] - MX);
    }
    float nov = novelty[idx];
    if (SM > 0.0f) { mxF[idx] = MX; rivF[idx] = nov / SM; punF[idx] = -1.0f; }
    else           { mxF[idx] = 0.0f; rivF[idx] = 0.0f; punF[idx] = nov * (1.0f / (float)M_); }
}

// ---------------------------------------------------------------------------
// update2_k: per 64-m block: MFMA scores -> P,P2 -> MFMA update GEMMs + cs;
// fused finalize. dbuf Wc/WcT staging; invn folded into P2.
// ---------------------------------------------------------------------------
__global__ __launch_bounds__(256) void update2_k(
    const us_t* __restrict__ Kbf, const us_t* __restrict__ Wcg,
    const us_t* __restrict__ WcTg, const float* __restrict__ g_em,
    const float* __restrict__ emK, const float* __restrict__ emV,
    const float* __restrict__ emS, const float* __restrict__ emAge,
    const float* __restrict__ raw_tau_w, const int* __restrict__ bp,
    const float* __restrict__ invnW, const float* __restrict__ mxF,
    const float* __restrict__ rivF, const float* __restrict__ punF,
    float* __restrict__ outK, float* __restrict__ outV,
    float* __restrict__ outS, float* __restrict__ outA)
{
    __shared__ us_t KaL[8192];
    __shared__ us_t WcL[2][8192];
    __shared__ us_t WcTL[2][8192];
    __shared__ us_t Pl[4096];
    __shared__ us_t P2l[4096];
    __shared__ float4 cns[2][64];
    __shared__ float sbL[64], csL[64], alphaL[64];

    const int tid = threadIdx.x;
    const int raw = blockIdx.x;
    const int logical = (raw & 7) * 32 + (raw >> 3);
    const int bs = logical >> 5;
    const int m0 = (logical & 31) * 64;
    const int b = bp[0];
    const float rtw = 1.0f / (softplus_(raw_tau_w[b]) + 0.1f);
    const float ge = g_em[bs];

    const us_t* KaG = Kbf + (size_t)bs * M_ * D_ + (size_t)m0 * D_;
    const us_t* WcB = Wcg + (size_t)bs * N_ * D_;
    const us_t* WcTB = WcTg + (size_t)bs * D_ * N_;

    for (int c = tid; c < 64 * 16; c += 256) {
        int row = c >> 4, off = (c & 15) << 3;
        uint4 v = *(const uint4*)&KaG[row * 128 + off];
        *(uint4*)&KaL[swz(row * 128 + off, row)] = v;
    }
    if (tid < 64) sbL[tid] = emS[((size_t)(bs * B_ + b)) * M_ + m0 + tid];
    __syncthreads();

    const int wave = tid >> 6, lane = tid & 63;
    const int r = lane & 15, kg = lane >> 4;
    const int mf = wave;

    bf8v a_s[4];
    #pragma unroll
    for (int kk = 0; kk < 4; ++kk) {
        int row = mf * 16 + r;
        a_s[kk] = *(bf8v*)&KaL[swz(row * 128 + kk * 32 + kg * 8, row)];
    }
    bool act4[4];
    #pragma unroll
    for (int reg = 0; reg < 4; ++reg) act4[reg] = (sbL[mf * 16 + kg * 4 + reg] > 0.0f);

    f4v cK[8], cV[8];
    #pragma unroll
    for (int df = 0; df < 8; ++df) { cK[df] = (f4v){0,0,0,0}; cV[df] = (f4v){0,0,0,0}; }
    float csp[4] = {0.f, 0.f, 0.f, 0.f};

    uint4 wr[4], wtr[4];
    float4 creg = {0.f, 0.f, 0.f, 0.f};

#define UP_LOAD(t) do {                                                            \
        for (int i = 0; i < 4; ++i) {                                              \
            int c = tid + i * 256;                                                 \
            wr[i]  = *(const uint4*)&WcB[((size_t)((t) * 64 + (c >> 4))) * D_ + ((c & 15) << 3)]; \
            wtr[i] = *(const uint4*)&WcTB[((size_t)(c >> 3)) * N_ + (t) * 64 + ((c & 7) << 3)];   \
        }                                                                          \
        if (tid < 64) {                                                            \
            int nn = (t) * 64 + tid;                                               \
            creg.x = mxF[(size_t)bs * N_ + nn];                                    \
            creg.y = rivF[(size_t)bs * N_ + nn];                                   \
            creg.z = punF[(size_t)bs * N_ + nn];                                   \
            creg.w = invnW[(size_t)bs * N_ + nn];                                  \
        }                                                                          \
    } while (0)

#define UP_WRITE(bf) do {                                                          \
        for (int i = 0; i < 4; ++i) {                                              \
            int c = tid + i * 256;                                                 \
            int ki = (c >> 4) * 128 + ((c & 15) << 3);                             \
            *(uint4*)&WcL[bf][swz(ki, c >> 4)] = wr[i];                            \
            int vi = (c >> 3) * 64 + ((c & 7) << 3);                               \
            *(uint4*)&WcTL[bf][swz(vi, c >> 3)] = wtr[i];                          \
        }                                                                          \
        if (tid < 64) cns[bf][tid] = creg;                                         \
    } while (0)

    UP_LOAD(0);
    UP_WRITE(0);
    __syncthreads();

    for (int nt = 0; nt < 16; ++nt) {
        const int cur = nt & 1;
        if (nt < 15) UP_LOAD(nt + 1);

        // scores + P/P2
        #pragma unroll
        for (int nf = 0; nf < 4; ++nf) {
            f4v c = {0.f, 0.f, 0.f, 0.f};
            #pragma unroll
            for (int kk = 0; kk < 4; ++kk) {
                int row = nf * 16 + r;
                bf8v bb = *(bf8v*)&WcL[cur][swz(row * 128 + kk * 32 + kg * 8, row)];
                c = __builtin_amdgcn_mfma_f32_16x16x32_bf16(a_s[kk], bb, c, 0, 0, 0);
            }
            int nl = nf * 16 + r;
            float4 cn = cns[cur][nl];
            #pragma unroll
            for (int reg = 0; reg < 4; ++reg) {
                float p;
                if (cn.z >= 0.0f) p = cn.z;
                else p = act4[reg] ? cn.y * __expf(c[reg] * cn.w * rtw - cn.x) : 0.0f;
                csp[reg] += p;
                int mrow = mf * 16 + kg * 4 + reg;
                Pl[swz(mrow * 64 + nl, mrow)] = f2bf(p);
                P2l[swz(mrow * 64 + nl, mrow)] = f2bf(p * cn.w);
            }
        }
        // update GEMMs
        #pragma unroll
        for (int kk2 = 0; kk2 < 2; ++kk2) {
            int prow = mf * 16 + r;
            bf8v pa  = *(bf8v*)&Pl[swz(prow * 64 + kk2 * 32 + kg * 8, prow)];
            bf8v pa2 = *(bf8v*)&P2l[swz(prow * 64 + kk2 * 32 + kg * 8, prow)];
            #pragma unroll
            for (int df = 0; df < 8; ++df) {
                int row = df * 16 + r;
                bf8v bw = *(bf8v*)&WcTL[cur][swz(row * 64 + kk2 * 32 + kg * 8, row)];
                cV[df] = __builtin_amdgcn_mfma_f32_16x16x32_bf16(pa, bw, cV[df], 0, 0, 0);
                cK[df] = __builtin_amdgcn_mfma_f32_16x16x32_bf16(pa2, bw, cK[df], 0, 0, 0);
            }
        }

        if (nt < 15) UP_WRITE(cur ^ 1);
        __syncthreads();
    }
#undef UP_LOAD
#undef UP_WRITE

    #pragma unroll
    for (int reg = 0; reg < 4; ++reg) {
        float v = csp[reg];
        v += __shfl_xor(v, 1, 16);
        v += __shfl_xor(v, 2, 16);
        v += __shfl_xor(v, 4, 16);
        v += __shfl_xor(v, 8, 16);
        csp[reg] = v;
    }
    if (r == 0) {
        #pragma unroll
        for (int reg = 0; reg < 4; ++reg) csL[mf * 16 + kg * 4 + reg] = csp[reg];
    }
    __syncthreads();
    if (tid < 64) alphaL[tid] = fminf(ge * csL[tid] * (1.0f / (float)N_), 1.0f);
    __syncthreads();

    float rden[4], nrm[4];
    #pragma unroll
    for (int reg = 0; reg < 4; ++reg) {
        int ml = mf * 16 + kg * 4 + reg;
        rden[reg] = 1.0f / fmaxf(csL[ml], 1e-8f);
        float s = 0.0f;
        #pragma unroll
        for (int df = 0; df < 8; ++df) {
            float u = cK[df][reg] * rden[reg];
            s += u * u;
        }
        s += __shfl_xor(s, 1, 16);
        s += __shfl_xor(s, 2, 16);
        s += __shfl_xor(s, 4, 16);
        s += __shfl_xor(s, 8, 16);
        nrm[reg] = 1.0f / fmaxf(sqrtf(s), 1e-12f);
    }

    const float* KbG = emK + ((size_t)(bs * B_ + b)) * M_ * D_ + (size_t)m0 * D_;
    const float* VbG = emV + ((size_t)(bs * B_ + b)) * M_ * D_ + (size_t)m0 * D_;
    float* oK = outK + (size_t)bs * M_ * D_ + (size_t)m0 * D_;
    float* oV = outV + (size_t)bs * M_ * D_ + (size_t)m0 * D_;
    #pragma unroll
    for (int reg = 0; reg < 4; ++reg) {
        int ml = mf * 16 + kg * 4 + reg;
        float a = alphaL[ml];
        #pragma unroll
        for (int df = 0; df < 8; ++df) {
            int d = df * 16 + r;
            float uK = cK[df][reg] * rden[reg] * nrm[reg];
            float uV = cV[df][reg] * rden[reg];
            oK[ml * D_ + d] = (1.0f - a) * KbG[ml * D_ + d] + a * uK;
            oV[ml * D_ + d] = (1.0f - a) * VbG[ml * D_ + d] + a * uV;
        }
    }
    if (tid < 64) {
        float a = alphaL[tid];
        float sp = fminf(fmaxf(sbL[tid] + a, 0.0f), 3.0f);
        outS[(size_t)bs * M_ + m0 + tid] = sp;
        outA[(size_t)bs * M_ + m0 + tid] =
            emAge[((size_t)(bs * B_ + b)) * M_ + m0 + tid] * (1.0f - a);
    }
}

// ---------------------------------------------------------------------------
__global__ __launch_bounds__(256) void scale_s_k(float* __restrict__ outS)
{
    __shared__ float wsum[4];
    const int bs = blockIdx.x, tid = threadIdx.x;
    float* p = outS + (size_t)bs * M_;
    float s = 0.0f;
    for (int i = tid; i < M_; i += 256) s += p[i];
    #pragma unroll
    for (int o = 32; o >= 1; o >>= 1) s += __shfl_xor(s, o, 64);
    if ((tid & 63) == 0) wsum[tid >> 6] = s;
    __syncthreads();
    float tot = wsum[0] + wsum[1] + wsum[2] + wsum[3];
    float scale = fminf(1.0f, 32.0f / fmaxf(tot, 1e-8f));
    for (int i = tid; i < M_; i += 256) p[i] *= scale;
}

// ---------------------------------------------------------------------------
extern "C" void kernel_launch(void* const* d_in, const int* in_sizes, int n_in,
                              void* d_out, int out_size, void* d_ws, size_t ws_size,
                              hipStream_t stream) {
    (void)in_sizes; (void)n_in; (void)out_size; (void)ws_size;
    const float* seed    = (const float*)d_in[0];
    const float* w_cand  = (const float*)d_in[1];
    const float* novelty = (const float*)d_in[2];
    const float* g_em    = (const float*)d_in[3];
    const float* emK     = (const float*)d_in[4];
    const float* emV     = (const float*)d_in[5];
    const float* emS     = (const float*)d_in[6];
    const float* emAge   = (const float*)d_in[7];
    const float* w1      = (const float*)d_in[8];
    const float* w2      = (const float*)d_in[9];
    const float* gb      = (const float*)d_in[10];
    const float* rt      = (const float*)d_in[11];
    const float* rtw     = (const float*)d_in[12];
    const int*   bp      = (const int*)d_in[13];

    float* out  = (float*)d_out;
    float* yem  = out;
    float* outK = out + 1048576;
    float* outV = out + 3145728;
    float* outS = out + 5242880;
    float* outA = out + 5259264;

    us_t* Kbf = (us_t*)d_ws;                               // 2,097,152 us
    us_t* Wcg = Kbf + (size_t)BS_ * M_ * D_;               // 1,048,576 us
    us_t* WcT = Wcg + (size_t)BS_ * N_ * D_;               // 1,048,576 us
    us_t* Vtg = WcT + (size_t)BS_ * D_ * N_;               // 2,097,152 us
    us_t* pDelta = Vtg + (size_t)BS_ * D_ * M_;            // 4,194,304 us
    float* fb   = (float*)(pDelta + (size_t)512 * 64 * 128);
    float* invnW = fb;                                     // 8192
    float* mxW   = invnW + BS_ * N_;                       // 32768
    float* smW   = mxW + 4 * BS_ * N_;                     // 32768
    float* mxF   = smW + 4 * BS_ * N_;                     // 8192
    float* rivF  = mxF + BS_ * N_;                         // 8192
    float* punF  = rivF + BS_ * N_;                        // 8192
    float* y1    = punF + BS_ * N_;                        // 1,048,576
    float2* pML  = (float2*)(y1 + (size_t)BS_ * N_ * D_);  // 32768 float2

    conv_k<<<dim3(80, 8), 256, 0, stream>>>(w_cand, emK, emV, bp, Kbf, Wcg, WcT, Vtg, invnW);

    attn_part_k<<<dim3(512), 256, 0, stream>>>(seed, Kbf, Vtg, emS, rt, bp, pDelta, pML);
    attn_merge_k<<<dim3(128), 256, 0, stream>>>(seed, seed, pDelta, pML, w1, w2, gb, bp, y1, 0);
    attn_part_k<<<dim3(512), 256, 0, stream>>>(y1, Kbf, Vtg, emS, rt, bp, pDelta, pML);
    attn_merge_k<<<dim3(128), 256, 0, stream>>>(y1, seed, pDelta, pML, w1, w2, gb, bp, yem, 1);

    stats_k<<<dim3(512), 256, 0, stream>>>(Wcg, Kbf, invnW, emS, rtw, bp, mxW, smW);
    stats_fin_k<<<dim3(32), 256, 0, stream>>>(mxW, smW, novelty, mxF, rivF, punF);
    update2_k<<<dim3(256), 256, 0, stream>>>(Kbf, Wcg, WcT, g_em, emK, emV, emS, emAge,
                                             rtw, bp, invnW, mxF, rivF, punF,
                                             outK, outV, outS, outA);
    scale_s_k<<<8, 256, 0, stream>>>(outS);
}